// Round 9
// baseline (376.489 us; speedup 1.0000x reference)
//
#include <hip/hip_runtime.h>
#include <hip/hip_fp16.h>
#include <math.h>

// ---------------------------------------------------------------------------
// GCN forward, fully fused, fp16 feature tables (fp32 accumulate), gathers
// sized to stay per-XCD-L2-resident (every random-gather table <= 3.2 MB).
//   xs     = fp16(dinv .* x)        [N,16] half (3.2 MB)
//   hs1_lo = fp16(dinv.*h1)[:,0:16] [N,16] half (3.2 MB)
//   hs1_hi = fp16(dinv.*h1)[:,16:32][N,16] half (3.2 MB)
// Edge layout: bucket b = 512 dst nodes, fixed-capacity gapped region of C
// edges at b*C (no histogram pre-pass needed). rowRange[n] = (beg,end) into
// the dst-sorted srcs[] array.
// Pipeline: init_cursor -> bucket_scatter -> bucket_finalize
//   -> gather_conv1 -> gather_conv2a -> gather_conv2b_head
// ---------------------------------------------------------------------------

#define BN 512           // nodes per bucket
#define BSH 9            // log2(BN)
#define NBUF 256         // max buckets (N <= 131072)
#define EPB 8192         // edges per scatter block

__global__ void init_cursor(int* __restrict__ gCursor, int NB, int C) {
    int b = blockIdx.x * blockDim.x + threadIdx.x;
    if (b < NB) gCursor[b] = b * C;
}

// Scatter edges into bucket-gapped packed array ((src<<9)|dstLocal).
__global__ void __launch_bounds__(256)
bucket_scatter(const int* __restrict__ row, const int* __restrict__ col,
               int* __restrict__ gCursor, int* __restrict__ packed,
               int E, int NB, int C) {
    __shared__ int hist[NBUF];
    __shared__ int base[NBUF];
    int t = threadIdx.x;
    int blockBase = blockIdx.x * EPB;
    for (int i = t; i < NB; i += 256) hist[i] = 0;
    __syncthreads();
    for (int i = t; i < EPB; i += 256) {           // pass 1: histogram
        int e = blockBase + i;
        if (e < E) atomicAdd(&hist[col[e] >> BSH], 1);
    }
    __syncthreads();
    for (int b = t; b < NB; b += 256) {            // claim global ranges
        int c = hist[b];
        base[b] = c ? atomicAdd(&gCursor[b], c) : 0;
        hist[b] = 0;
    }
    __syncthreads();
    for (int i = t; i < EPB; i += 256) {           // pass 2: rank + write
        int e = blockBase + i;
        if (e < E) {
            int c = col[e];
            int b = c >> BSH;
            int r = atomicAdd(&hist[b], 1);
            int pos = base[b] + r;
            if (pos < (b + 1) * C)                 // overflow guard (8-sigma margin)
                packed[pos] = (row[e] << BSH) | (c & (BN - 1));
        }
    }
}

// Per bucket: degree hist -> rowRange + dinv, counting-sort -> srcs[],
// prescale xs = fp16(dinv .* x).
__global__ void __launch_bounds__(256)
bucket_finalize(const int* __restrict__ packed, const int* __restrict__ gCursor,
                int2* __restrict__ rowRange, float* __restrict__ dinv,
                int* __restrict__ srcs, const float4* __restrict__ x4,
                __half* __restrict__ xs, int N, int C) {
    __shared__ int cnt[BN];
    __shared__ int ps[256];
    __shared__ int cur[BN];
    __shared__ float sdv[BN];
    int bkt = blockIdx.x;
    int t = threadIdx.x;
    int nodeBase = bkt << BSH;
    cnt[t] = 0;
    cnt[t + 256] = 0;
    __syncthreads();
    int beg = bkt * C;
    int end = min(gCursor[bkt], beg + C);
    for (int e = beg + t; e < end; e += 256)
        atomicAdd(&cnt[packed[e] & (BN - 1)], 1);
    __syncthreads();
    int v0 = cnt[2 * t], v1 = cnt[2 * t + 1];
    int s = v0 + v1;
    ps[t] = s;
    __syncthreads();
    for (int off = 1; off < 256; off <<= 1) {      // inclusive scan of pair sums
        int u = (t >= off) ? ps[t - off] : 0;
        __syncthreads();
        ps[t] += u;
        __syncthreads();
    }
    int p0 = beg + ps[t] - s;                      // exclusive prefix
    int p1 = p0 + v0;
    cur[2 * t] = p0;
    cur[2 * t + 1] = p1;
    float d0 = rsqrtf((float)v0 + 1.0f);
    float d1 = rsqrtf((float)v1 + 1.0f);
    sdv[2 * t] = d0;
    sdv[2 * t + 1] = d1;
    int n0 = nodeBase + 2 * t, n1 = n0 + 1;
    if (n0 < N) { rowRange[n0] = make_int2(p0, p1); dinv[n0] = d0; }
    if (n1 < N) { rowRange[n1] = make_int2(p1, p1 + v1); dinv[n1] = d1; }
    __syncthreads();
    for (int e = beg + t; e < end; e += 256) {     // counting sort (2nd read: L2)
        int w = packed[e];
        int pos = atomicAdd(&cur[w & (BN - 1)], 1);
        srcs[pos] = w >> BSH;
    }
    // prescale: xs = fp16(dinv .* x); 2 threads/node, 16B (8 halves) each
    for (int i = t; i < BN * 2; i += 256) {
        int n = i >> 1, hf = i & 1;
        int g = nodeBase + n;
        if (g < N) {
            float d = sdv[n];
            float4 va = x4[(size_t)g * 4 + hf * 2];
            float4 vb = x4[(size_t)g * 4 + hf * 2 + 1];
            __half2 h0 = __floats2half2_rn(va.x * d, va.y * d);
            __half2 h1 = __floats2half2_rn(va.z * d, va.w * d);
            __half2 h2 = __floats2half2_rn(vb.x * d, vb.y * d);
            __half2 h3 = __floats2half2_rn(vb.z * d, vb.w * d);
            uint4 u;
            u.x = *(unsigned*)&h0; u.y = *(unsigned*)&h1;
            u.z = *(unsigned*)&h2; u.w = *(unsigned*)&h3;
            *(uint4*)(xs + (size_t)g * 16 + hf * 8) = u;
        }
    }
}

__device__ __forceinline__ void acc8(float* a, uint4 u) {
    float2 f;
    f = __half22float2(*(const __half2*)&u.x); a[0] += f.x; a[1] += f.y;
    f = __half22float2(*(const __half2*)&u.y); a[2] += f.x; a[3] += f.y;
    f = __half22float2(*(const __half2*)&u.z); a[4] += f.x; a[5] += f.y;
    f = __half22float2(*(const __half2*)&u.w); a[6] += f.x; a[7] += f.y;
}

// Layer 1: gather xs (16ch half), fused W1 GEMM + bias + ReLU;
// writes hs1 split lo/hi fp16 tables. 2 lanes/node; block = 128 nodes.
__global__ void __launch_bounds__(256)
gather_conv1(const int2* __restrict__ rowRange, const int* __restrict__ srcs,
             const __half* __restrict__ xs, const float* __restrict__ dinv,
             const float* __restrict__ W1, const float* __restrict__ b1,
             __half* __restrict__ hs1lo, __half* __restrict__ hs1hi, int N) {
    __shared__ float A[128][17];
    __shared__ float sW[16 * 32];
    __shared__ float sb[32];
    int t = threadIdx.x;
    for (int i = t; i < 512; i += 256) sW[i] = W1[i];
    if (t < 32) sb[t] = b1[t];
    int tt = blockIdx.x * 256 + t;
    int node = tt >> 1, q = tt & 1, ln = t >> 1;
    float a[8] = {0.f, 0.f, 0.f, 0.f, 0.f, 0.f, 0.f, 0.f};
    float di = 0.f;
    if (node < N) {
        int2 rr = rowRange[node];
        int e = rr.x;
        for (; e + 1 < rr.y; e += 2) {
            int s0 = __builtin_nontemporal_load(&srcs[e]);
            int s1 = __builtin_nontemporal_load(&srcs[e + 1]);
            uint4 u0 = *(const uint4*)(xs + (size_t)s0 * 16 + q * 8);
            uint4 u1 = *(const uint4*)(xs + (size_t)s1 * 16 + q * 8);
            acc8(a, u0);
            acc8(a, u1);
        }
        if (e < rr.y) {
            int s0 = __builtin_nontemporal_load(&srcs[e]);
            acc8(a, *(const uint4*)(xs + (size_t)s0 * 16 + q * 8));
        }
        acc8(a, *(const uint4*)(xs + (size_t)node * 16 + q * 8));   // self
        di = dinv[node];
#pragma unroll
        for (int j = 0; j < 8; ++j) a[j] *= di;
    }
#pragma unroll
    for (int j = 0; j < 8; ++j) A[ln][q * 8 + j] = a[j];
    __syncthreads();
    if (node < N) {
        int k0 = q * 16;
        float acc[16];
#pragma unroll
        for (int j = 0; j < 16; ++j) acc[j] = sb[k0 + j];
#pragma unroll
        for (int c = 0; c < 16; ++c) {
            float ac = A[ln][c];
#pragma unroll
            for (int j = 0; j < 16; ++j) acc[j] += ac * sW[c * 32 + k0 + j];
        }
        __half2 h[8];
#pragma unroll
        for (int j = 0; j < 8; ++j)
            h[j] = __floats2half2_rn(di * fmaxf(acc[2 * j], 0.f),
                                     di * fmaxf(acc[2 * j + 1], 0.f));
        uint4 u0, u1;
        u0.x = *(unsigned*)&h[0]; u0.y = *(unsigned*)&h[1];
        u0.z = *(unsigned*)&h[2]; u0.w = *(unsigned*)&h[3];
        u1.x = *(unsigned*)&h[4]; u1.y = *(unsigned*)&h[5];
        u1.z = *(unsigned*)&h[6]; u1.w = *(unsigned*)&h[7];
        __half* tbl = q ? hs1hi : hs1lo;           // channels q*16..q*16+15
        *(uint4*)(tbl + (size_t)node * 16) = u0;
        *(uint4*)(tbl + (size_t)node * 16 + 8) = u1;
    }
}

// Conv2 pass A: gather hs1_lo (3.2MB, L2-resident) -> A2lo[N,16] fp32.
__global__ void __launch_bounds__(256)
gather_conv2a(const int2* __restrict__ rowRange, const int* __restrict__ srcs,
              const __half* __restrict__ hs1lo, const float* __restrict__ dinv,
              float* __restrict__ A2lo, int N) {
    int tt = blockIdx.x * 256 + threadIdx.x;
    int node = tt >> 1, q = tt & 1;
    if (node >= N) return;
    float a[8] = {0.f, 0.f, 0.f, 0.f, 0.f, 0.f, 0.f, 0.f};
    int2 rr = rowRange[node];
    int e = rr.x;
    for (; e + 1 < rr.y; e += 2) {
        int s0 = __builtin_nontemporal_load(&srcs[e]);
        int s1 = __builtin_nontemporal_load(&srcs[e + 1]);
        uint4 u0 = *(const uint4*)(hs1lo + (size_t)s0 * 16 + q * 8);
        uint4 u1 = *(const uint4*)(hs1lo + (size_t)s1 * 16 + q * 8);
        acc8(a, u0);
        acc8(a, u1);
    }
    if (e < rr.y) {
        int s0 = __builtin_nontemporal_load(&srcs[e]);
        acc8(a, *(const uint4*)(hs1lo + (size_t)node * 0 + (size_t)s0 * 16 + q * 8));
    }
    acc8(a, *(const uint4*)(hs1lo + (size_t)node * 16 + q * 8));    // self
    float di = dinv[node];
    float4 r0, r1;
    r0.x = a[0] * di; r0.y = a[1] * di; r0.z = a[2] * di; r0.w = a[3] * di;
    r1.x = a[4] * di; r1.y = a[5] * di; r1.z = a[6] * di; r1.w = a[7] * di;
    *(float4*)(A2lo + (size_t)node * 16 + q * 8) = r0;
    *(float4*)(A2lo + (size_t)node * 16 + q * 8 + 4) = r1;
}

// Conv2 pass B + head: gather hs1_hi, combine with A2lo, W2+b2+ReLU,
// Wl1+bl1+ReLU, Wl4+bl4 -> out. 2 lanes/node; block = 128 nodes.
__global__ void __launch_bounds__(256)
gather_conv2b_head(const int2* __restrict__ rowRange, const int* __restrict__ srcs,
                   const __half* __restrict__ hs1hi, const float* __restrict__ A2lo,
                   const float* __restrict__ dinv,
                   const float* __restrict__ W2, const float* __restrict__ b2,
                   const float* __restrict__ Wl1, const float* __restrict__ bl1,
                   const float* __restrict__ Wl4, const float* __restrict__ bl4,
                   float* __restrict__ out, int N) {
    __shared__ float A[128][33];
    __shared__ float sW2[1024];
    __shared__ float sWl1[1024];
    __shared__ float sb2[32], sbl1[32], sWl4[32];
    __shared__ float sbl4;
    int t = threadIdx.x;
    for (int i = t; i < 1024; i += 256) { sW2[i] = W2[i]; sWl1[i] = Wl1[i]; }
    if (t < 32) { sb2[t] = b2[t]; sbl1[t] = bl1[t]; sWl4[t] = Wl4[t]; }
    if (t == 0) sbl4 = bl4[0];
    int tt = blockIdx.x * 256 + t;
    int node = tt >> 1, q = tt & 1, ln = t >> 1;
    float a[8] = {0.f, 0.f, 0.f, 0.f, 0.f, 0.f, 0.f, 0.f};
    if (node < N) {
        int2 rr = rowRange[node];
        int e = rr.x;
        for (; e + 1 < rr.y; e += 2) {
            int s0 = __builtin_nontemporal_load(&srcs[e]);
            int s1 = __builtin_nontemporal_load(&srcs[e + 1]);
            uint4 u0 = *(const uint4*)(hs1hi + (size_t)s0 * 16 + q * 8);
            uint4 u1 = *(const uint4*)(hs1hi + (size_t)s1 * 16 + q * 8);
            acc8(a, u0);
            acc8(a, u1);
        }
        if (e < rr.y) {
            int s0 = __builtin_nontemporal_load(&srcs[e]);
            acc8(a, *(const uint4*)(hs1hi + (size_t)s0 * 16 + q * 8));
        }
        acc8(a, *(const uint4*)(hs1hi + (size_t)node * 16 + q * 8)); // self
        float di = dinv[node];
#pragma unroll
        for (int j = 0; j < 8; ++j) a[j] *= di;
        // low half from pass A (coalesced)
        float4 l0 = *(const float4*)(A2lo + (size_t)node * 16 + q * 8);
        float4 l1 = *(const float4*)(A2lo + (size_t)node * 16 + q * 8 + 4);
        A[ln][q * 8 + 0] = l0.x; A[ln][q * 8 + 1] = l0.y;
        A[ln][q * 8 + 2] = l0.z; A[ln][q * 8 + 3] = l0.w;
        A[ln][q * 8 + 4] = l1.x; A[ln][q * 8 + 5] = l1.y;
        A[ln][q * 8 + 6] = l1.z; A[ln][q * 8 + 7] = l1.w;
    }
#pragma unroll
    for (int j = 0; j < 8; ++j) A[ln][16 + q * 8 + j] = a[j];
    __syncthreads();
    int k0 = q * 16;
    float h2[16];
#pragma unroll
    for (int j = 0; j < 16; ++j) h2[j] = sb2[k0 + j];
#pragma unroll
    for (int c = 0; c < 32; ++c) {
        float ac = A[ln][c];
#pragma unroll
        for (int j = 0; j < 16; ++j) h2[j] += ac * sW2[c * 32 + k0 + j];
    }
#pragma unroll
    for (int j = 0; j < 16; ++j) h2[j] = fmaxf(h2[j], 0.f);
    __syncthreads();
#pragma unroll
    for (int j = 0; j < 16; ++j) A[ln][k0 + j] = h2[j];
    __syncthreads();
    float h3[16];
#pragma unroll
    for (int j = 0; j < 16; ++j) h3[j] = sbl1[k0 + j];
#pragma unroll
    for (int c = 0; c < 32; ++c) {
        float ac = A[ln][c];
#pragma unroll
        for (int j = 0; j < 16; ++j) h3[j] += ac * sWl1[c * 32 + k0 + j];
    }
    float p = 0.f;
#pragma unroll
    for (int j = 0; j < 16; ++j) p += fmaxf(h3[j], 0.f) * sWl4[k0 + j];
    p += __shfl_xor(p, 1);
    if (q == 0 && node < N) out[node] = p + sbl4;
}

extern "C" void kernel_launch(void* const* d_in, const int* in_sizes, int n_in,
                              void* d_out, int out_size, void* d_ws, size_t ws_size,
                              hipStream_t stream) {
    const float* x   = (const float*)d_in[0];
    const int*   ei  = (const int*)d_in[1];
    const float* W1  = (const float*)d_in[2];
    const float* b1  = (const float*)d_in[3];
    const float* W2  = (const float*)d_in[4];
    const float* b2  = (const float*)d_in[5];
    const float* Wl1 = (const float*)d_in[6];
    const float* bl1 = (const float*)d_in[7];
    const float* Wl4 = (const float*)d_in[8];
    const float* bl4 = (const float*)d_in[9];
    float* out = (float*)d_out;

    const int N = in_sizes[0] / 16;
    const int E = in_sizes[1] / 2;
    const int* row = ei;        // edge_index[0] : source j
    const int* col = ei + E;    // edge_index[1] : target i
    const int NB = (N + BN - 1) >> BSH;
    // fixed per-bucket capacity: mean * 1.125, rounded up to 64
    int C = (E + NB - 1) / NB;
    C = (C * 9 + 7) / 8;
    C = (C + 63) & ~63;

    // workspace layout (512B aligned)
    char* ws = (char*)d_ws;
    auto align = [](size_t v) { return (v + 511) & ~(size_t)511; };
    size_t o = 0;
    int*    gCursor  = (int*)(ws + o);    o = align(o + (size_t)NBUF * 4);
    int2*   rowRange = (int2*)(ws + o);   o = align(o + (size_t)N * 8);
    float*  dinv     = (float*)(ws + o);  o = align(o + (size_t)N * 4);
    int*    packed   = (int*)(ws + o);    o = align(o + (size_t)NB * C * 4);
    int*    srcs     = (int*)(ws + o);    o = align(o + (size_t)NB * C * 4);
    __half* xs       = (__half*)(ws + o); o = align(o + (size_t)N * 16 * 2);
    __half* hs1lo    = (__half*)(ws + o); o = align(o + (size_t)N * 16 * 2);
    __half* hs1hi    = (__half*)(ws + o); o = align(o + (size_t)N * 16 * 2);
    float*  A2lo     = (float*)(ws + o);  o = align(o + (size_t)N * 16 * 4);

    const int BLK = 256;
    int gridSc = (E + EPB - 1) / EPB;
    int gridG  = (N * 2 + BLK - 1) / BLK;

    // --- edge reorder + degrees + prescale ---
    init_cursor<<<1, BLK, 0, stream>>>(gCursor, NB, C);
    bucket_scatter<<<gridSc, BLK, 0, stream>>>(row, col, gCursor, packed, E, NB, C);
    bucket_finalize<<<NB, BLK, 0, stream>>>(packed, gCursor, rowRange, dinv, srcs,
                                            (const float4*)x, xs, N, C);

    // --- conv1 (gather xs + fused W1) ---
    gather_conv1<<<gridG, BLK, 0, stream>>>(rowRange, srcs, xs, dinv, W1, b1,
                                            hs1lo, hs1hi, N);

    // --- conv2 split passes + fused head ---
    gather_conv2a<<<gridG, BLK, 0, stream>>>(rowRange, srcs, hs1lo, dinv, A2lo, N);
    gather_conv2b_head<<<gridG, BLK, 0, stream>>>(rowRange, srcs, hs1hi, A2lo, dinv,
                                                  W2, b2, Wl1, bl1, Wl4, bl4, out, N);
}

// Round 10
// 308.095 us; speedup vs baseline: 1.2220x; 1.2220x over previous
//
#include <hip/hip_runtime.h>
#include <hip/hip_fp16.h>
#include <math.h>

// ---------------------------------------------------------------------------
// GCN forward, fully fused, fp16 feature tables (fp32 accumulate).
//   xs  = fp16(dinv .* x)   [N,16] half (3.2 MB, L2-resident)
//   hs1 = fp16(dinv .* h1)  [N,32] half (6.4 MB)
// Edge lists are sorted by (dstLocal, srcHalf): within each dst node's list,
// lower-half srcs come first -> at any instant the conv2 gather's hot set is
// one 3.2 MB half of hs1, which fits a 4 MiB per-XCD L2.
// Edge layout: bucket b = 512 dst nodes, fixed-capacity gapped region of C
// edges at b*C (no histogram pre-pass). rowRange[n]=(beg,end) into srcs[].
// Pipeline: init_cursor -> bucket_scatter -> bucket_finalize
//   -> gather_conv1 -> gather_conv2_head
// ---------------------------------------------------------------------------

#define BN 512           // nodes per bucket
#define BSH 9            // log2(BN)
#define NBUF 256         // max buckets (N <= 131072)
#define EPB 8192         // edges per scatter block

__global__ void init_cursor(int* __restrict__ gCursor, int NB, int C) {
    int b = blockIdx.x * blockDim.x + threadIdx.x;
    if (b < NB) gCursor[b] = b * C;
}

// Scatter edges into bucket-gapped packed array ((src<<9)|dstLocal).
__global__ void __launch_bounds__(256)
bucket_scatter(const int* __restrict__ row, const int* __restrict__ col,
               int* __restrict__ gCursor, int* __restrict__ packed,
               int E, int NB, int C) {
    __shared__ int hist[NBUF];
    __shared__ int base[NBUF];
    int t = threadIdx.x;
    int blockBase = blockIdx.x * EPB;
    for (int i = t; i < NB; i += 256) hist[i] = 0;
    __syncthreads();
    for (int i = t; i < EPB; i += 256) {           // pass 1: histogram
        int e = blockBase + i;
        if (e < E) atomicAdd(&hist[col[e] >> BSH], 1);
    }
    __syncthreads();
    for (int b = t; b < NB; b += 256) {            // claim global ranges
        int c = hist[b];
        base[b] = c ? atomicAdd(&gCursor[b], c) : 0;
        hist[b] = 0;
    }
    __syncthreads();
    for (int i = t; i < EPB; i += 256) {           // pass 2: rank + write
        int e = blockBase + i;
        if (e < E) {
            int c = col[e];
            int b = c >> BSH;
            int r = atomicAdd(&hist[b], 1);
            int pos = base[b] + r;
            if (pos < (b + 1) * C)                 // overflow guard (>8 sigma)
                packed[pos] = (row[e] << BSH) | (c & (BN - 1));
        }
    }
}

// Per bucket: degree hist (1024 bins = dstLocal*2 + srcHalf) -> rowRange +
// dinv, counting-sort -> srcs[] ordered (dl, srcHalf), prescale xs.
__global__ void __launch_bounds__(256)
bucket_finalize(const int* __restrict__ packed, const int* __restrict__ gCursor,
                int2* __restrict__ rowRange, float* __restrict__ dinv,
                int* __restrict__ srcs, const float4* __restrict__ x4,
                __half* __restrict__ xs, int N, int C, int halfN) {
    __shared__ int cnt[BN * 2];
    __shared__ int ps[256];
    __shared__ int cur[BN * 2];
    __shared__ float sdv[BN];
    int bkt = blockIdx.x;
    int t = threadIdx.x;
    int nodeBase = bkt << BSH;
#pragma unroll
    for (int j = 0; j < 4; ++j) cnt[t * 4 + j] = 0;
    __syncthreads();
    int beg = bkt * C;
    int end = min(gCursor[bkt], beg + C);
    for (int e = beg + t; e < end; e += 256) {
        int w = packed[e];
        int key = ((w & (BN - 1)) << 1) | ((w >> BSH) >= halfN ? 1 : 0);
        atomicAdd(&cnt[key], 1);
    }
    __syncthreads();
    // thread t owns bins 4t..4t+3 = nodes 2t, 2t+1
    int c0 = cnt[4 * t], c1 = cnt[4 * t + 1], c2 = cnt[4 * t + 2], c3 = cnt[4 * t + 3];
    int s = c0 + c1 + c2 + c3;
    ps[t] = s;
    __syncthreads();
    for (int off = 1; off < 256; off <<= 1) {      // inclusive scan of sums
        int u = (t >= off) ? ps[t - off] : 0;
        __syncthreads();
        ps[t] += u;
        __syncthreads();
    }
    int p = beg + ps[t] - s;                       // exclusive prefix
    cur[4 * t] = p;
    cur[4 * t + 1] = p + c0;
    cur[4 * t + 2] = p + c0 + c1;
    cur[4 * t + 3] = p + c0 + c1 + c2;
    int v0 = c0 + c1, v1 = c2 + c3;                // node degrees
    float d0 = rsqrtf((float)v0 + 1.0f);
    float d1 = rsqrtf((float)v1 + 1.0f);
    sdv[2 * t] = d0;
    sdv[2 * t + 1] = d1;
    int n0 = nodeBase + 2 * t, n1 = n0 + 1;
    if (n0 < N) { rowRange[n0] = make_int2(p, p + v0); dinv[n0] = d0; }
    if (n1 < N) { rowRange[n1] = make_int2(p + v0, p + v0 + v1); dinv[n1] = d1; }
    __syncthreads();
    for (int e = beg + t; e < end; e += 256) {     // counting sort (2nd read: L2)
        int w = packed[e];
        int src = w >> BSH;
        int key = ((w & (BN - 1)) << 1) | (src >= halfN ? 1 : 0);
        int pos = atomicAdd(&cur[key], 1);
        srcs[pos] = src;
    }
    // prescale: xs = fp16(dinv .* x); 2 threads/node, 16B (8 halves) each
    for (int i = t; i < BN * 2; i += 256) {
        int n = i >> 1, hf = i & 1;
        int g = nodeBase + n;
        if (g < N) {
            float d = sdv[n];
            float4 va = x4[(size_t)g * 4 + hf * 2];
            float4 vb = x4[(size_t)g * 4 + hf * 2 + 1];
            __half2 h0 = __floats2half2_rn(va.x * d, va.y * d);
            __half2 h1 = __floats2half2_rn(va.z * d, va.w * d);
            __half2 h2 = __floats2half2_rn(vb.x * d, vb.y * d);
            __half2 h3 = __floats2half2_rn(vb.z * d, vb.w * d);
            uint4 u;
            u.x = *(unsigned*)&h0; u.y = *(unsigned*)&h1;
            u.z = *(unsigned*)&h2; u.w = *(unsigned*)&h3;
            *(uint4*)(xs + (size_t)g * 16 + hf * 8) = u;
        }
    }
}

__device__ __forceinline__ void acc8(float* a, uint4 u) {
    float2 f;
    f = __half22float2(*(const __half2*)&u.x); a[0] += f.x; a[1] += f.y;
    f = __half22float2(*(const __half2*)&u.y); a[2] += f.x; a[3] += f.y;
    f = __half22float2(*(const __half2*)&u.z); a[4] += f.x; a[5] += f.y;
    f = __half22float2(*(const __half2*)&u.w); a[6] += f.x; a[7] += f.y;
}

// Layer 1: gather xs (16ch half), fused W1 GEMM + bias + ReLU; hs1=fp16(dinv.*h1).
// 2 lanes per node, 16B each; block = 128 nodes.
__global__ void __launch_bounds__(256)
gather_conv1(const int2* __restrict__ rowRange, const int* __restrict__ srcs,
             const __half* __restrict__ xs, const float* __restrict__ dinv,
             const float* __restrict__ W1, const float* __restrict__ b1,
             __half* __restrict__ hs1, int N) {
    __shared__ float A[128][17];
    __shared__ float sW[16 * 32];
    __shared__ float sb[32];
    int t = threadIdx.x;
    for (int i = t; i < 512; i += 256) sW[i] = W1[i];
    if (t < 32) sb[t] = b1[t];
    int tt = blockIdx.x * 256 + t;
    int node = tt >> 1, q = tt & 1, ln = t >> 1;
    float a[8] = {0.f, 0.f, 0.f, 0.f, 0.f, 0.f, 0.f, 0.f};
    float di = 0.f;
    if (node < N) {
        int2 rr = rowRange[node];
        int e = rr.x;
        for (; e + 1 < rr.y; e += 2) {
            int s0 = __builtin_nontemporal_load(&srcs[e]);
            int s1 = __builtin_nontemporal_load(&srcs[e + 1]);
            uint4 u0 = *(const uint4*)(xs + (size_t)s0 * 16 + q * 8);
            uint4 u1 = *(const uint4*)(xs + (size_t)s1 * 16 + q * 8);
            acc8(a, u0);
            acc8(a, u1);
        }
        if (e < rr.y) {
            int s0 = __builtin_nontemporal_load(&srcs[e]);
            acc8(a, *(const uint4*)(xs + (size_t)s0 * 16 + q * 8));
        }
        acc8(a, *(const uint4*)(xs + (size_t)node * 16 + q * 8));   // self
        di = dinv[node];
#pragma unroll
        for (int j = 0; j < 8; ++j) a[j] *= di;
    }
#pragma unroll
    for (int j = 0; j < 8; ++j) A[ln][q * 8 + j] = a[j];
    __syncthreads();
    if (node < N) {
        int k0 = q * 16;
        float acc[16];
#pragma unroll
        for (int j = 0; j < 16; ++j) acc[j] = sb[k0 + j];
#pragma unroll
        for (int c = 0; c < 16; ++c) {
            float ac = A[ln][c];
#pragma unroll
            for (int j = 0; j < 16; ++j) acc[j] += ac * sW[c * 32 + k0 + j];
        }
        __half2 h[8];
#pragma unroll
        for (int j = 0; j < 8; ++j)
            h[j] = __floats2half2_rn(di * fmaxf(acc[2 * j], 0.f),
                                     di * fmaxf(acc[2 * j + 1], 0.f));
        uint4 u0, u1;
        u0.x = *(unsigned*)&h[0]; u0.y = *(unsigned*)&h[1];
        u0.z = *(unsigned*)&h[2]; u0.w = *(unsigned*)&h[3];
        u1.x = *(unsigned*)&h[4]; u1.y = *(unsigned*)&h[5];
        u1.z = *(unsigned*)&h[6]; u1.w = *(unsigned*)&h[7];
        *(uint4*)(hs1 + (size_t)node * 32 + k0) = u0;
        *(uint4*)(hs1 + (size_t)node * 32 + k0 + 8) = u1;
    }
}

// Layer 2 + head: gather hs1 (32ch half), fused W2+b2+ReLU, Wl1+bl1+ReLU,
// Wl4+bl4. 4 lanes per node, 16B each; block = 64 nodes. Writes out[N].
__global__ void __launch_bounds__(256)
gather_conv2_head(const int2* __restrict__ rowRange, const int* __restrict__ srcs,
                  const __half* __restrict__ hs1, const float* __restrict__ dinv,
                  const float* __restrict__ W2, const float* __restrict__ b2,
                  const float* __restrict__ Wl1, const float* __restrict__ bl1,
                  const float* __restrict__ Wl4, const float* __restrict__ bl4,
                  float* __restrict__ out, int N) {
    __shared__ float A[64][33];
    __shared__ float sW2[1024];
    __shared__ float sWl1[1024];
    __shared__ float sb2[32], sbl1[32], sWl4[32];
    __shared__ float sbl4;
    int t = threadIdx.x;
    for (int i = t; i < 1024; i += 256) { sW2[i] = W2[i]; sWl1[i] = Wl1[i]; }
    if (t < 32) { sb2[t] = b2[t]; sbl1[t] = bl1[t]; sWl4[t] = Wl4[t]; }
    if (t == 0) sbl4 = bl4[0];
    int tt = blockIdx.x * 256 + t;
    int node = tt >> 2, q = tt & 3, ln = t >> 2;
    float a[8] = {0.f, 0.f, 0.f, 0.f, 0.f, 0.f, 0.f, 0.f};
    if (node < N) {
        int2 rr = rowRange[node];
        int e = rr.x;
        for (; e + 1 < rr.y; e += 2) {
            int s0 = __builtin_nontemporal_load(&srcs[e]);
            int s1 = __builtin_nontemporal_load(&srcs[e + 1]);
            uint4 u0 = *(const uint4*)(hs1 + (size_t)s0 * 32 + q * 8);
            uint4 u1 = *(const uint4*)(hs1 + (size_t)s1 * 32 + q * 8);
            acc8(a, u0);
            acc8(a, u1);
        }
        if (e < rr.y) {
            int s0 = __builtin_nontemporal_load(&srcs[e]);
            acc8(a, *(const uint4*)(hs1 + (size_t)s0 * 32 + q * 8));
        }
        acc8(a, *(const uint4*)(hs1 + (size_t)node * 32 + q * 8));  // self
        float di = dinv[node];
#pragma unroll
        for (int j = 0; j < 8; ++j) a[j] *= di;
    }
#pragma unroll
    for (int j = 0; j < 8; ++j) A[ln][q * 8 + j] = a[j];
    __syncthreads();
    int k0 = q * 8;
    float h2[8];
#pragma unroll
    for (int j = 0; j < 8; ++j) h2[j] = sb2[k0 + j];
#pragma unroll
    for (int c = 0; c < 32; ++c) {
        float ac = A[ln][c];
#pragma unroll
        for (int j = 0; j < 8; ++j) h2[j] += ac * sW2[c * 32 + k0 + j];
    }
#pragma unroll
    for (int j = 0; j < 8; ++j) h2[j] = fmaxf(h2[j], 0.f);
    __syncthreads();
#pragma unroll
    for (int j = 0; j < 8; ++j) A[ln][k0 + j] = h2[j];
    __syncthreads();
    float h3[8];
#pragma unroll
    for (int j = 0; j < 8; ++j) h3[j] = sbl1[k0 + j];
#pragma unroll
    for (int c = 0; c < 32; ++c) {
        float ac = A[ln][c];
#pragma unroll
        for (int j = 0; j < 8; ++j) h3[j] += ac * sWl1[c * 32 + k0 + j];
    }
    float p = 0.f;
#pragma unroll
    for (int j = 0; j < 8; ++j) p += fmaxf(h3[j], 0.f) * sWl4[k0 + j];
    p += __shfl_xor(p, 1);
    p += __shfl_xor(p, 2);
    if (q == 0 && node < N) out[node] = p + sbl4;
}

extern "C" void kernel_launch(void* const* d_in, const int* in_sizes, int n_in,
                              void* d_out, int out_size, void* d_ws, size_t ws_size,
                              hipStream_t stream) {
    const float* x   = (const float*)d_in[0];
    const int*   ei  = (const int*)d_in[1];
    const float* W1  = (const float*)d_in[2];
    const float* b1  = (const float*)d_in[3];
    const float* W2  = (const float*)d_in[4];
    const float* b2  = (const float*)d_in[5];
    const float* Wl1 = (const float*)d_in[6];
    const float* bl1 = (const float*)d_in[7];
    const float* Wl4 = (const float*)d_in[8];
    const float* bl4 = (const float*)d_in[9];
    float* out = (float*)d_out;

    const int N = in_sizes[0] / 16;
    const int E = in_sizes[1] / 2;
    const int* row = ei;        // edge_index[0] : source j
    const int* col = ei + E;    // edge_index[1] : target i
    const int NB = (N + BN - 1) >> BSH;
    const int halfN = N / 2;
    // fixed per-bucket capacity: mean * 1.125, rounded up to 64
    int C = (E + NB - 1) / NB;
    C = (C * 9 + 7) / 8;
    C = (C + 63) & ~63;

    // workspace layout (512B aligned)
    char* ws = (char*)d_ws;
    auto align = [](size_t v) { return (v + 511) & ~(size_t)511; };
    size_t o = 0;
    int*    gCursor  = (int*)(ws + o);    o = align(o + (size_t)NBUF * 4);
    int2*   rowRange = (int2*)(ws + o);   o = align(o + (size_t)N * 8);
    float*  dinv     = (float*)(ws + o);  o = align(o + (size_t)N * 4);
    int*    packed   = (int*)(ws + o);    o = align(o + (size_t)NB * C * 4);
    int*    srcs     = (int*)(ws + o);    o = align(o + (size_t)NB * C * 4);
    __half* xs       = (__half*)(ws + o); o = align(o + (size_t)N * 16 * 2);
    __half* hs1      = (__half*)(ws + o); o = align(o + (size_t)N * 32 * 2);

    const int BLK = 256;
    int gridSc = (E + EPB - 1) / EPB;
    int gridG1 = (N * 2 + BLK - 1) / BLK;
    int gridG2 = (N * 4 + BLK - 1) / BLK;

    // --- edge reorder + degrees + prescale ---
    init_cursor<<<1, BLK, 0, stream>>>(gCursor, NB, C);
    bucket_scatter<<<gridSc, BLK, 0, stream>>>(row, col, gCursor, packed, E, NB, C);
    bucket_finalize<<<NB, BLK, 0, stream>>>(packed, gCursor, rowRange, dinv, srcs,
                                            (const float4*)x, xs, N, C, halfN);

    // --- conv1 (gather xs + fused W1) ---
    gather_conv1<<<gridG1, BLK, 0, stream>>>(rowRange, srcs, xs, dinv, W1, b1, hs1, N);

    // --- conv2 + MLP head, fully fused ---
    gather_conv2_head<<<gridG2, BLK, 0, stream>>>(rowRange, srcs, hs1, dinv,
                                                  W2, b2, Wl1, bl1, Wl4, bl4, out, N);
}

// Round 11
// 281.982 us; speedup vs baseline: 1.3352x; 1.0926x over previous
//
#include <hip/hip_runtime.h>
#include <hip/hip_fp16.h>
#include <math.h>

// ---------------------------------------------------------------------------
// GCN forward, fully fused, fp16 feature tables (fp32 accumulate).
//   xs  = fp16(dinv .* x)   [N,16] half (3.2 MB, L2-resident)
//   hs1 = fp16(dinv .* h1)  [N,32] half (6.4 MB)
// Edge layout: bucket b = 512 dst nodes, fixed-capacity gapped region of C
// edges at b*C (no histogram pre-pass; C = mean*1.125, ~16 sigma margin).
// rowRange[n]=(beg,end) into dst-sorted srcs[].
// Pipeline: init_cursor -> bucket_scatter -> bucket_finalize
//   -> gather_conv1 -> gather_conv2_head          (round-8 conv kernels)
// ---------------------------------------------------------------------------

#define BN 512           // nodes per bucket
#define BSH 9            // log2(BN)
#define NBUF 256         // max buckets (N <= 131072)
#define EPB 8192         // edges per scatter block

__global__ void init_cursor(int* __restrict__ gCursor, int NB, int C) {
    int b = blockIdx.x * blockDim.x + threadIdx.x;
    if (b < NB) gCursor[b] = b * C;
}

// Scatter edges into bucket-gapped packed array ((src<<9)|dstLocal).
__global__ void __launch_bounds__(256)
bucket_scatter(const int* __restrict__ row, const int* __restrict__ col,
               int* __restrict__ gCursor, int* __restrict__ packed,
               int E, int NB, int C) {
    __shared__ int hist[NBUF];
    __shared__ int base[NBUF];
    int t = threadIdx.x;
    int blockBase = blockIdx.x * EPB;
    for (int i = t; i < NB; i += 256) hist[i] = 0;
    __syncthreads();
    for (int i = t; i < EPB; i += 256) {           // pass 1: histogram
        int e = blockBase + i;
        if (e < E) atomicAdd(&hist[col[e] >> BSH], 1);
    }
    __syncthreads();
    for (int b = t; b < NB; b += 256) {            // claim global ranges
        int c = hist[b];
        base[b] = c ? atomicAdd(&gCursor[b], c) : 0;
        hist[b] = 0;
    }
    __syncthreads();
    for (int i = t; i < EPB; i += 256) {           // pass 2: rank + write
        int e = blockBase + i;
        if (e < E) {
            int c = col[e];
            int b = c >> BSH;
            int r = atomicAdd(&hist[b], 1);
            int pos = base[b] + r;
            if (pos < (b + 1) * C)                 // overflow guard (~16 sigma)
                packed[pos] = (row[e] << BSH) | (c & (BN - 1));
        }
    }
}

// Per bucket: degree hist -> rowRange + dinv (pair-scan over 512 with 256
// threads), counting-sort -> srcs[], prescale xs = fp16(dinv .* x).
__global__ void __launch_bounds__(256)
bucket_finalize(const int* __restrict__ packed, const int* __restrict__ gCursor,
                int2* __restrict__ rowRange, float* __restrict__ dinv,
                int* __restrict__ srcs, const float4* __restrict__ x4,
                __half* __restrict__ xs, int N, int C) {
    __shared__ int cnt[BN];
    __shared__ int ps[256];
    __shared__ int cur[BN];
    __shared__ float sdv[BN];
    int bkt = blockIdx.x;
    int t = threadIdx.x;
    int nodeBase = bkt << BSH;
    cnt[t] = 0;
    cnt[t + 256] = 0;
    __syncthreads();
    int beg = bkt * C;
    int end = min(gCursor[bkt], beg + C);
    for (int e = beg + t; e < end; e += 256)
        atomicAdd(&cnt[packed[e] & (BN - 1)], 1);
    __syncthreads();
    int v0 = cnt[2 * t], v1 = cnt[2 * t + 1];
    int s = v0 + v1;
    ps[t] = s;
    __syncthreads();
    for (int off = 1; off < 256; off <<= 1) {      // inclusive scan of pair sums
        int u = (t >= off) ? ps[t - off] : 0;
        __syncthreads();
        ps[t] += u;
        __syncthreads();
    }
    int p0 = beg + ps[t] - s;                      // exclusive prefix
    int p1 = p0 + v0;
    cur[2 * t] = p0;
    cur[2 * t + 1] = p1;
    float d0 = rsqrtf((float)v0 + 1.0f);
    float d1 = rsqrtf((float)v1 + 1.0f);
    sdv[2 * t] = d0;
    sdv[2 * t + 1] = d1;
    int n0 = nodeBase + 2 * t, n1 = n0 + 1;
    if (n0 < N) { rowRange[n0] = make_int2(p0, p1); dinv[n0] = d0; }
    if (n1 < N) { rowRange[n1] = make_int2(p1, p1 + v1); dinv[n1] = d1; }
    __syncthreads();
    for (int e = beg + t; e < end; e += 256) {     // counting sort (2nd read: L2)
        int w = packed[e];
        int pos = atomicAdd(&cur[w & (BN - 1)], 1);
        srcs[pos] = w >> BSH;
    }
    // prescale: xs = fp16(dinv .* x); 2 threads/node, 16B (8 halves) each
    for (int i = t; i < BN * 2; i += 256) {
        int n = i >> 1, hf = i & 1;
        int g = nodeBase + n;
        if (g < N) {
            float d = sdv[n];
            float4 va = x4[(size_t)g * 4 + hf * 2];
            float4 vb = x4[(size_t)g * 4 + hf * 2 + 1];
            __half2 h0 = __floats2half2_rn(va.x * d, va.y * d);
            __half2 h1 = __floats2half2_rn(va.z * d, va.w * d);
            __half2 h2 = __floats2half2_rn(vb.x * d, vb.y * d);
            __half2 h3 = __floats2half2_rn(vb.z * d, vb.w * d);
            uint4 u;
            u.x = *(unsigned*)&h0; u.y = *(unsigned*)&h1;
            u.z = *(unsigned*)&h2; u.w = *(unsigned*)&h3;
            *(uint4*)(xs + (size_t)g * 16 + hf * 8) = u;
        }
    }
}

__device__ __forceinline__ void acc8(float* a, uint4 u) {
    float2 f;
    f = __half22float2(*(const __half2*)&u.x); a[0] += f.x; a[1] += f.y;
    f = __half22float2(*(const __half2*)&u.y); a[2] += f.x; a[3] += f.y;
    f = __half22float2(*(const __half2*)&u.z); a[4] += f.x; a[5] += f.y;
    f = __half22float2(*(const __half2*)&u.w); a[6] += f.x; a[7] += f.y;
}

// Layer 1: gather xs (16ch half), fused W1 GEMM + bias + ReLU; hs1=fp16(dinv.*h1).
// 2 lanes per node, 16B each; block = 128 nodes.  (round-8 body)
__global__ void __launch_bounds__(256)
gather_conv1(const int2* __restrict__ rowRange, const int* __restrict__ srcs,
             const __half* __restrict__ xs, const float* __restrict__ dinv,
             const float* __restrict__ W1, const float* __restrict__ b1,
             __half* __restrict__ hs1, int N) {
    __shared__ float A[128][17];
    __shared__ float sW[16 * 32];
    __shared__ float sb[32];
    int t = threadIdx.x;
    for (int i = t; i < 512; i += 256) sW[i] = W1[i];
    if (t < 32) sb[t] = b1[t];
    int tt = blockIdx.x * 256 + t;
    int node = tt >> 1, q = tt & 1, ln = t >> 1;
    float a[8] = {0.f, 0.f, 0.f, 0.f, 0.f, 0.f, 0.f, 0.f};
    float di = 0.f;
    if (node < N) {
        int2 rr = rowRange[node];
        for (int e = rr.x; e < rr.y; ++e) {
            int s = srcs[e];
            acc8(a, *(const uint4*)(xs + (size_t)s * 16 + q * 8));
        }
        acc8(a, *(const uint4*)(xs + (size_t)node * 16 + q * 8));   // self
        di = dinv[node];
#pragma unroll
        for (int j = 0; j < 8; ++j) a[j] *= di;
    }
#pragma unroll
    for (int j = 0; j < 8; ++j) A[ln][q * 8 + j] = a[j];
    __syncthreads();
    if (node < N) {
        int k0 = q * 16;
        float acc[16];
#pragma unroll
        for (int j = 0; j < 16; ++j) acc[j] = sb[k0 + j];
#pragma unroll
        for (int c = 0; c < 16; ++c) {
            float ac = A[ln][c];
#pragma unroll
            for (int j = 0; j < 16; ++j) acc[j] += ac * sW[c * 32 + k0 + j];
        }
        __half2 h[8];
#pragma unroll
        for (int j = 0; j < 8; ++j)
            h[j] = __floats2half2_rn(di * fmaxf(acc[2 * j], 0.f),
                                     di * fmaxf(acc[2 * j + 1], 0.f));
        uint4 u0, u1;
        u0.x = *(unsigned*)&h[0]; u0.y = *(unsigned*)&h[1];
        u0.z = *(unsigned*)&h[2]; u0.w = *(unsigned*)&h[3];
        u1.x = *(unsigned*)&h[4]; u1.y = *(unsigned*)&h[5];
        u1.z = *(unsigned*)&h[6]; u1.w = *(unsigned*)&h[7];
        *(uint4*)(hs1 + (size_t)node * 32 + k0) = u0;
        *(uint4*)(hs1 + (size_t)node * 32 + k0 + 8) = u1;
    }
}

// Layer 2 + head: gather hs1 (32ch half), fused W2+b2+ReLU, Wl1+bl1+ReLU,
// Wl4+bl4. 4 lanes per node, 16B each; block = 64 nodes.  (round-8 body)
__global__ void __launch_bounds__(256)
gather_conv2_head(const int2* __restrict__ rowRange, const int* __restrict__ srcs,
                  const __half* __restrict__ hs1, const float* __restrict__ dinv,
                  const float* __restrict__ W2, const float* __restrict__ b2,
                  const float* __restrict__ Wl1, const float* __restrict__ bl1,
                  const float* __restrict__ Wl4, const float* __restrict__ bl4,
                  float* __restrict__ out, int N) {
    __shared__ float A[64][33];
    __shared__ float sW2[1024];
    __shared__ float sWl1[1024];
    __shared__ float sb2[32], sbl1[32], sWl4[32];
    __shared__ float sbl4;
    int t = threadIdx.x;
    for (int i = t; i < 1024; i += 256) { sW2[i] = W2[i]; sWl1[i] = Wl1[i]; }
    if (t < 32) { sb2[t] = b2[t]; sbl1[t] = bl1[t]; sWl4[t] = Wl4[t]; }
    if (t == 0) sbl4 = bl4[0];
    int tt = blockIdx.x * 256 + t;
    int node = tt >> 2, q = tt & 3, ln = t >> 2;
    float a[8] = {0.f, 0.f, 0.f, 0.f, 0.f, 0.f, 0.f, 0.f};
    if (node < N) {
        int2 rr = rowRange[node];
        for (int e = rr.x; e < rr.y; ++e) {
            int s = srcs[e];
            acc8(a, *(const uint4*)(hs1 + (size_t)s * 32 + q * 8));
        }
        acc8(a, *(const uint4*)(hs1 + (size_t)node * 32 + q * 8));  // self
        float di = dinv[node];
#pragma unroll
        for (int j = 0; j < 8; ++j) a[j] *= di;
    }
#pragma unroll
    for (int j = 0; j < 8; ++j) A[ln][q * 8 + j] = a[j];
    __syncthreads();
    int k0 = q * 8;
    float h2[8];
#pragma unroll
    for (int j = 0; j < 8; ++j) h2[j] = sb2[k0 + j];
#pragma unroll
    for (int c = 0; c < 32; ++c) {
        float ac = A[ln][c];
#pragma unroll
        for (int j = 0; j < 8; ++j) h2[j] += ac * sW2[c * 32 + k0 + j];
    }
#pragma unroll
    for (int j = 0; j < 8; ++j) h2[j] = fmaxf(h2[j], 0.f);
    __syncthreads();
#pragma unroll
    for (int j = 0; j < 8; ++j) A[ln][k0 + j] = h2[j];
    __syncthreads();
    float h3[8];
#pragma unroll
    for (int j = 0; j < 8; ++j) h3[j] = sbl1[k0 + j];
#pragma unroll
    for (int c = 0; c < 32; ++c) {
        float ac = A[ln][c];
#pragma unroll
        for (int j = 0; j < 8; ++j) h3[j] += ac * sWl1[c * 32 + k0 + j];
    }
    float p = 0.f;
#pragma unroll
    for (int j = 0; j < 8; ++j) p += fmaxf(h3[j], 0.f) * sWl4[k0 + j];
    p += __shfl_xor(p, 1);
    p += __shfl_xor(p, 2);
    if (q == 0 && node < N) out[node] = p + sbl4;
}

extern "C" void kernel_launch(void* const* d_in, const int* in_sizes, int n_in,
                              void* d_out, int out_size, void* d_ws, size_t ws_size,
                              hipStream_t stream) {
    const float* x   = (const float*)d_in[0];
    const int*   ei  = (const int*)d_in[1];
    const float* W1  = (const float*)d_in[2];
    const float* b1  = (const float*)d_in[3];
    const float* W2  = (const float*)d_in[4];
    const float* b2  = (const float*)d_in[5];
    const float* Wl1 = (const float*)d_in[6];
    const float* bl1 = (const float*)d_in[7];
    const float* Wl4 = (const float*)d_in[8];
    const float* bl4 = (const float*)d_in[9];
    float* out = (float*)d_out;

    const int N = in_sizes[0] / 16;
    const int E = in_sizes[1] / 2;
    const int* row = ei;        // edge_index[0] : source j
    const int* col = ei + E;    // edge_index[1] : target i
    const int NB = (N + BN - 1) >> BSH;
    // fixed per-bucket capacity: mean * 1.125, rounded up to 64
    int C = (E + NB - 1) / NB;
    C = (C * 9 + 7) / 8;
    C = (C + 63) & ~63;

    // workspace layout (512B aligned)
    char* ws = (char*)d_ws;
    auto align = [](size_t v) { return (v + 511) & ~(size_t)511; };
    size_t o = 0;
    int*    gCursor  = (int*)(ws + o);    o = align(o + (size_t)NBUF * 4);
    int2*   rowRange = (int2*)(ws + o);   o = align(o + (size_t)N * 8);
    float*  dinv     = (float*)(ws + o);  o = align(o + (size_t)N * 4);
    int*    packed   = (int*)(ws + o);    o = align(o + (size_t)NB * C * 4);
    int*    srcs     = (int*)(ws + o);    o = align(o + (size_t)NB * C * 4);
    __half* xs       = (__half*)(ws + o); o = align(o + (size_t)N * 16 * 2);
    __half* hs1      = (__half*)(ws + o); o = align(o + (size_t)N * 32 * 2);

    const int BLK = 256;
    int gridSc = (E + EPB - 1) / EPB;
    int gridG1 = (N * 2 + BLK - 1) / BLK;
    int gridG2 = (N * 4 + BLK - 1) / BLK;

    // --- edge reorder + degrees + prescale ---
    init_cursor<<<1, BLK, 0, stream>>>(gCursor, NB, C);
    bucket_scatter<<<gridSc, BLK, 0, stream>>>(row, col, gCursor, packed, E, NB, C);
    bucket_finalize<<<NB, BLK, 0, stream>>>(packed, gCursor, rowRange, dinv, srcs,
                                            (const float4*)x, xs, N, C);

    // --- conv1 (gather xs + fused W1) ---
    gather_conv1<<<gridG1, BLK, 0, stream>>>(rowRange, srcs, xs, dinv, W1, b1, hs1, N);

    // --- conv2 + MLP head, fully fused ---
    gather_conv2_head<<<gridG2, BLK, 0, stream>>>(rowRange, srcs, hs1, dinv,
                                                  W2, b2, Wl1, bl1, Wl4, bl4, out, N);
}

// Round 12
// 256.600 us; speedup vs baseline: 1.4672x; 1.0989x over previous
//
#include <hip/hip_runtime.h>
#include <hip/hip_fp16.h>
#include <math.h>

// ---------------------------------------------------------------------------
// GCN forward, fully fused, fp16 feature tables (fp32 accumulate).
//   xs  = fp16(dinv .* x)   [N,16] half (3.2 MB, L2-resident)
//   hs1 = fp16(dinv .* h1)  [N,32] half (6.4 MB)
// Edge layout: bucket b = 512 dst nodes, fixed-capacity gapped region of C
// edges at b*C (no histogram pre-pass; C = mean*1.125, ~16 sigma margin).
// rowRange[n]=(beg,end) into dst-sorted srcs[].
// Pipeline: init_cursor -> bucket_scatter (single-pass rank, reg-staged)
//   -> bucket_finalize (1024 thr) -> gather_conv1 -> gather_conv2_head
// ---------------------------------------------------------------------------

#define BN 512           // nodes per bucket
#define BSH 9            // log2(BN)
#define NBUF 256         // max buckets (N <= 131072)
#define EPB 4096         // edges per scatter block
#define EPT 16           // edges per scatter thread (EPB/256)

__global__ void init_cursor(int* __restrict__ gCursor, int NB, int C) {
    int b = blockIdx.x * blockDim.x + threadIdx.x;
    if (b < NB) gCursor[b] = b * C;
}

// Scatter edges into bucket-gapped packed array ((src<<9)|dstLocal).
// Single LDS-atomic pass: rank recorded in registers, then claim + write.
__global__ void __launch_bounds__(256)
bucket_scatter(const int* __restrict__ row, const int* __restrict__ col,
               int* __restrict__ gCursor, int* __restrict__ packed,
               int E, int NB, int C) {
    __shared__ int hist[NBUF];
    __shared__ int base[NBUF];
    int t = threadIdx.x;
    int blockBase = blockIdx.x * EPB;
    for (int i = t; i < NB; i += 256) hist[i] = 0;
    __syncthreads();
    int pay[EPT];
    int meta[EPT];
#pragma unroll
    for (int k = 0; k < EPT; ++k) {
        int e = blockBase + k * 256 + t;
        if (e < E) {
            int c = col[e];
            int b = c >> BSH;
            int r = atomicAdd(&hist[b], 1);        // rank within (block,bucket)
            pay[k] = (row[e] << BSH) | (c & (BN - 1));
            meta[k] = (b << 16) | r;               // r < 4096 fits 16 bits
        } else {
            meta[k] = -1;
        }
    }
    __syncthreads();
    for (int b = t; b < NB; b += 256) {            // claim global ranges
        int c = hist[b];
        base[b] = c ? atomicAdd(&gCursor[b], c) : 0;
    }
    __syncthreads();
#pragma unroll
    for (int k = 0; k < EPT; ++k) {                // write
        int m = meta[k];
        if (m >= 0) {
            int b = m >> 16;
            int pos = base[b] + (m & 0xFFFF);
            if (pos < (b + 1) * C)                 // overflow guard (~16 sigma)
                packed[pos] = pay[k];
        }
    }
}

// Per bucket (1024 threads, 16 waves): degree hist -> rowRange + dinv,
// counting-sort -> srcs[], prescale xs = fp16(dinv .* x).
__global__ void __launch_bounds__(1024)
bucket_finalize(const int* __restrict__ packed, const int* __restrict__ gCursor,
                int2* __restrict__ rowRange, float* __restrict__ dinv,
                int* __restrict__ srcs, const float4* __restrict__ x4,
                __half* __restrict__ xs, int N, int C) {
    __shared__ int cnt[BN];
    __shared__ int sc[BN];
    __shared__ int cur[BN];
    __shared__ float sdv[BN];
    int bkt = blockIdx.x;
    int t = threadIdx.x;
    int nodeBase = bkt << BSH;
    if (t < BN) cnt[t] = 0;
    __syncthreads();
    int beg = bkt * C;
    int end = min(gCursor[bkt], beg + C);
    for (int e = beg + t; e < end; e += 1024)
        atomicAdd(&cnt[packed[e] & (BN - 1)], 1);
    __syncthreads();
    if (t < BN) sc[t] = cnt[t];
    __syncthreads();
    for (int off = 1; off < BN; off <<= 1) {       // inclusive Hillis-Steele
        int u = 0;
        if (t < BN && t >= off) u = sc[t - off];
        __syncthreads();
        if (t < BN) sc[t] += u;
        __syncthreads();
    }
    if (t < BN) {
        int v = cnt[t];
        int p = beg + sc[t] - v;                   // exclusive prefix
        cur[t] = p;
        float d = rsqrtf((float)v + 1.0f);
        sdv[t] = d;
        int n = nodeBase + t;
        if (n < N) { rowRange[n] = make_int2(p, p + v); dinv[n] = d; }
    }
    __syncthreads();
    for (int e = beg + t; e < end; e += 1024) {    // counting sort (2nd read: L2)
        int w = packed[e];
        int pos = atomicAdd(&cur[w & (BN - 1)], 1);
        srcs[pos] = w >> BSH;
    }
    // prescale: xs = fp16(dinv .* x); 2 threads/node, 16B (8 halves) each
    {
        int i = t;                                  // BN*2 == 1024 exactly
        int n = i >> 1, hf = i & 1;
        int g = nodeBase + n;
        if (g < N) {
            float d = sdv[n];
            float4 va = x4[(size_t)g * 4 + hf * 2];
            float4 vb = x4[(size_t)g * 4 + hf * 2 + 1];
            __half2 h0 = __floats2half2_rn(va.x * d, va.y * d);
            __half2 h1 = __floats2half2_rn(va.z * d, va.w * d);
            __half2 h2 = __floats2half2_rn(vb.x * d, vb.y * d);
            __half2 h3 = __floats2half2_rn(vb.z * d, vb.w * d);
            uint4 u;
            u.x = *(unsigned*)&h0; u.y = *(unsigned*)&h1;
            u.z = *(unsigned*)&h2; u.w = *(unsigned*)&h3;
            *(uint4*)(xs + (size_t)g * 16 + hf * 8) = u;
        }
    }
}

__device__ __forceinline__ void acc8(float* a, uint4 u) {
    float2 f;
    f = __half22float2(*(const __half2*)&u.x); a[0] += f.x; a[1] += f.y;
    f = __half22float2(*(const __half2*)&u.y); a[2] += f.x; a[3] += f.y;
    f = __half22float2(*(const __half2*)&u.z); a[4] += f.x; a[5] += f.y;
    f = __half22float2(*(const __half2*)&u.w); a[6] += f.x; a[7] += f.y;
}

// Layer 1: gather xs (16ch half), fused W1 GEMM + bias + ReLU; hs1=fp16(dinv.*h1).
// 2 lanes per node, 16B each; block = 128 nodes.  (round-8 body)
__global__ void __launch_bounds__(256)
gather_conv1(const int2* __restrict__ rowRange, const int* __restrict__ srcs,
             const __half* __restrict__ xs, const float* __restrict__ dinv,
             const float* __restrict__ W1, const float* __restrict__ b1,
             __half* __restrict__ hs1, int N) {
    __shared__ float A[128][17];
    __shared__ float sW[16 * 32];
    __shared__ float sb[32];
    int t = threadIdx.x;
    for (int i = t; i < 512; i += 256) sW[i] = W1[i];
    if (t < 32) sb[t] = b1[t];
    int tt = blockIdx.x * 256 + t;
    int node = tt >> 1, q = tt & 1, ln = t >> 1;
    float a[8] = {0.f, 0.f, 0.f, 0.f, 0.f, 0.f, 0.f, 0.f};
    float di = 0.f;
    if (node < N) {
        int2 rr = rowRange[node];
        for (int e = rr.x; e < rr.y; ++e) {
            int s = srcs[e];
            acc8(a, *(const uint4*)(xs + (size_t)s * 16 + q * 8));
        }
        acc8(a, *(const uint4*)(xs + (size_t)node * 16 + q * 8));   // self
        di = dinv[node];
#pragma unroll
        for (int j = 0; j < 8; ++j) a[j] *= di;
    }
#pragma unroll
    for (int j = 0; j < 8; ++j) A[ln][q * 8 + j] = a[j];
    __syncthreads();
    if (node < N) {
        int k0 = q * 16;
        float acc[16];
#pragma unroll
        for (int j = 0; j < 16; ++j) acc[j] = sb[k0 + j];
#pragma unroll
        for (int c = 0; c < 16; ++c) {
            float ac = A[ln][c];
#pragma unroll
            for (int j = 0; j < 16; ++j) acc[j] += ac * sW[c * 32 + k0 + j];
        }
        __half2 h[8];
#pragma unroll
        for (int j = 0; j < 8; ++j)
            h[j] = __floats2half2_rn(di * fmaxf(acc[2 * j], 0.f),
                                     di * fmaxf(acc[2 * j + 1], 0.f));
        uint4 u0, u1;
        u0.x = *(unsigned*)&h[0]; u0.y = *(unsigned*)&h[1];
        u0.z = *(unsigned*)&h[2]; u0.w = *(unsigned*)&h[3];
        u1.x = *(unsigned*)&h[4]; u1.y = *(unsigned*)&h[5];
        u1.z = *(unsigned*)&h[6]; u1.w = *(unsigned*)&h[7];
        *(uint4*)(hs1 + (size_t)node * 32 + k0) = u0;
        *(uint4*)(hs1 + (size_t)node * 32 + k0 + 8) = u1;
    }
}

// Layer 2 + head: gather hs1 (32ch half), fused W2+b2+ReLU, Wl1+bl1+ReLU,
// Wl4+bl4. 4 lanes per node, 16B each; block = 64 nodes.  (round-8 body)
__global__ void __launch_bounds__(256)
gather_conv2_head(const int2* __restrict__ rowRange, const int* __restrict__ srcs,
                  const __half* __restrict__ hs1, const float* __restrict__ dinv,
                  const float* __restrict__ W2, const float* __restrict__ b2,
                  const float* __restrict__ Wl1, const float* __restrict__ bl1,
                  const float* __restrict__ Wl4, const float* __restrict__ bl4,
                  float* __restrict__ out, int N) {
    __shared__ float A[64][33];
    __shared__ float sW2[1024];
    __shared__ float sWl1[1024];
    __shared__ float sb2[32], sbl1[32], sWl4[32];
    __shared__ float sbl4;
    int t = threadIdx.x;
    for (int i = t; i < 1024; i += 256) { sW2[i] = W2[i]; sWl1[i] = Wl1[i]; }
    if (t < 32) { sb2[t] = b2[t]; sbl1[t] = bl1[t]; sWl4[t] = Wl4[t]; }
    if (t == 0) sbl4 = bl4[0];
    int tt = blockIdx.x * 256 + t;
    int node = tt >> 2, q = tt & 3, ln = t >> 2;
    float a[8] = {0.f, 0.f, 0.f, 0.f, 0.f, 0.f, 0.f, 0.f};
    if (node < N) {
        int2 rr = rowRange[node];
        for (int e = rr.x; e < rr.y; ++e) {
            int s = srcs[e];
            acc8(a, *(const uint4*)(hs1 + (size_t)s * 32 + q * 8));
        }
        acc8(a, *(const uint4*)(hs1 + (size_t)node * 32 + q * 8));  // self
        float di = dinv[node];
#pragma unroll
        for (int j = 0; j < 8; ++j) a[j] *= di;
    }
#pragma unroll
    for (int j = 0; j < 8; ++j) A[ln][q * 8 + j] = a[j];
    __syncthreads();
    int k0 = q * 8;
    float h2[8];
#pragma unroll
    for (int j = 0; j < 8; ++j) h2[j] = sb2[k0 + j];
#pragma unroll
    for (int c = 0; c < 32; ++c) {
        float ac = A[ln][c];
#pragma unroll
        for (int j = 0; j < 8; ++j) h2[j] += ac * sW2[c * 32 + k0 + j];
    }
#pragma unroll
    for (int j = 0; j < 8; ++j) h2[j] = fmaxf(h2[j], 0.f);
    __syncthreads();
#pragma unroll
    for (int j = 0; j < 8; ++j) A[ln][k0 + j] = h2[j];
    __syncthreads();
    float h3[8];
#pragma unroll
    for (int j = 0; j < 8; ++j) h3[j] = sbl1[k0 + j];
#pragma unroll
    for (int c = 0; c < 32; ++c) {
        float ac = A[ln][c];
#pragma unroll
        for (int j = 0; j < 8; ++j) h3[j] += ac * sWl1[c * 32 + k0 + j];
    }
    float p = 0.f;
#pragma unroll
    for (int j = 0; j < 8; ++j) p += fmaxf(h3[j], 0.f) * sWl4[k0 + j];
    p += __shfl_xor(p, 1);
    p += __shfl_xor(p, 2);
    if (q == 0 && node < N) out[node] = p + sbl4;
}

extern "C" void kernel_launch(void* const* d_in, const int* in_sizes, int n_in,
                              void* d_out, int out_size, void* d_ws, size_t ws_size,
                              hipStream_t stream) {
    const float* x   = (const float*)d_in[0];
    const int*   ei  = (const int*)d_in[1];
    const float* W1  = (const float*)d_in[2];
    const float* b1  = (const float*)d_in[3];
    const float* W2  = (const float*)d_in[4];
    const float* b2  = (const float*)d_in[5];
    const float* Wl1 = (const float*)d_in[6];
    const float* bl1 = (const float*)d_in[7];
    const float* Wl4 = (const float*)d_in[8];
    const float* bl4 = (const float*)d_in[9];
    float* out = (float*)d_out;

    const int N = in_sizes[0] / 16;
    const int E = in_sizes[1] / 2;
    const int* row = ei;        // edge_index[0] : source j
    const int* col = ei + E;    // edge_index[1] : target i
    const int NB = (N + BN - 1) >> BSH;
    // fixed per-bucket capacity: mean * 1.125, rounded up to 64
    int C = (E + NB - 1) / NB;
    C = (C * 9 + 7) / 8;
    C = (C + 63) & ~63;

    // workspace layout (512B aligned)
    char* ws = (char*)d_ws;
    auto align = [](size_t v) { return (v + 511) & ~(size_t)511; };
    size_t o = 0;
    int*    gCursor  = (int*)(ws + o);    o = align(o + (size_t)NBUF * 4);
    int2*   rowRange = (int2*)(ws + o);   o = align(o + (size_t)N * 8);
    float*  dinv     = (float*)(ws + o);  o = align(o + (size_t)N * 4);
    int*    packed   = (int*)(ws + o);    o = align(o + (size_t)NB * C * 4);
    int*    srcs     = (int*)(ws + o);    o = align(o + (size_t)NB * C * 4);
    __half* xs       = (__half*)(ws + o); o = align(o + (size_t)N * 16 * 2);
    __half* hs1      = (__half*)(ws + o); o = align(o + (size_t)N * 32 * 2);

    const int BLK = 256;
    int gridSc = (E + EPB - 1) / EPB;
    int gridG1 = (N * 2 + BLK - 1) / BLK;
    int gridG2 = (N * 4 + BLK - 1) / BLK;

    // --- edge reorder + degrees + prescale ---
    init_cursor<<<1, BLK, 0, stream>>>(gCursor, NB, C);
    bucket_scatter<<<gridSc, BLK, 0, stream>>>(row, col, gCursor, packed, E, NB, C);
    bucket_finalize<<<NB, 1024, 0, stream>>>(packed, gCursor, rowRange, dinv, srcs,
                                             (const float4*)x, xs, N, C);

    // --- conv1 (gather xs + fused W1) ---
    gather_conv1<<<gridG1, BLK, 0, stream>>>(rowRange, srcs, xs, dinv, W1, b1, hs1, N);

    // --- conv2 + MLP head, fully fused ---
    gather_conv2_head<<<gridG2, BLK, 0, stream>>>(rowRange, srcs, hs1, dinv,
                                                  W2, b2, Wl1, bl1, Wl4, bl4, out, N);
}

// Round 14
// 251.399 us; speedup vs baseline: 1.4976x; 1.0207x over previous
//
#include <hip/hip_runtime.h>
#include <hip/hip_fp16.h>
#include <math.h>

// ---------------------------------------------------------------------------
// GCN forward, fully fused, fp16 feature tables (fp32 accumulate).
//   xs  = fp16(dinv .* x)   [N,16] half (3.2 MB, L2-resident)
//   hs1 = fp16(dinv .* h1)  [N,32] half (6.4 MB)
// Edge layout: bucket b = 512 dst nodes, fixed-capacity gapped region of C
// edges at b*C. Lists sorted by (dstLocal, srcHalf): rowRange[n]=(beg,end),
// rowMid[n] = boundary between srcs < N/2 and srcs >= N/2.
// conv2 runs as two kernels so each one's random working set is one 3.2 MB
// contiguous half of hs1 (fits a 4 MiB per-XCD L2):
//   gather_conv2_lo : sum lo-half srcs -> A2[N,32] fp32 (coalesced)
//   gather_conv2_hi_head : hi-half + self + A2 partial, fused W2/b2/ReLU +
//                          Wl1/bl1/ReLU + Wl4/bl4 -> out
// ---------------------------------------------------------------------------

#define BN 512           // nodes per bucket
#define BSH 9            // log2(BN)
#define NBUF 256         // max buckets (N <= 131072)
#define EPB 4096         // edges per scatter block
#define EPT 16           // edges per scatter thread (EPB/256)

__global__ void init_cursor(int* __restrict__ gCursor, int NB, int C) {
    int b = blockIdx.x * blockDim.x + threadIdx.x;
    if (b < NB) gCursor[b] = b * C;
}

// Scatter edges into bucket-gapped packed array ((src<<9)|dstLocal).
// Single LDS-atomic pass: rank recorded in registers, then claim + write.
__global__ void __launch_bounds__(256)
bucket_scatter(const int* __restrict__ row, const int* __restrict__ col,
               int* __restrict__ gCursor, int* __restrict__ packed,
               int E, int NB, int C) {
    __shared__ int hist[NBUF];
    __shared__ int base[NBUF];
    int t = threadIdx.x;
    int blockBase = blockIdx.x * EPB;
    for (int i = t; i < NB; i += 256) hist[i] = 0;
    __syncthreads();
    int pay[EPT];
    int meta[EPT];
#pragma unroll
    for (int k = 0; k < EPT; ++k) {
        int e = blockBase + k * 256 + t;
        if (e < E) {
            int c = col[e];
            int b = c >> BSH;
            int r = atomicAdd(&hist[b], 1);        // rank within (block,bucket)
            pay[k] = (row[e] << BSH) | (c & (BN - 1));
            meta[k] = (b << 16) | r;               // r < 4096 fits 16 bits
        } else {
            meta[k] = -1;
        }
    }
    __syncthreads();
    for (int b = t; b < NB; b += 256) {            // claim global ranges
        int c = hist[b];
        base[b] = c ? atomicAdd(&gCursor[b], c) : 0;
    }
    __syncthreads();
#pragma unroll
    for (int k = 0; k < EPT; ++k) {                // write
        int m = meta[k];
        if (m >= 0) {
            int b = m >> 16;
            int pos = base[b] + (m & 0xFFFF);
            if (pos < (b + 1) * C)                 // overflow guard (~16 sigma)
                packed[pos] = pay[k];
        }
    }
}

// Per bucket (1024 threads): 1024-bin hist (dstLocal*2 + srcHalf) -> rowRange
// + rowMid + dinv, counting-sort -> srcs[] ordered (dl, srcHalf), prescale xs.
__global__ void __launch_bounds__(1024)
bucket_finalize(const int* __restrict__ packed, const int* __restrict__ gCursor,
                int2* __restrict__ rowRange, int* __restrict__ rowMid,
                float* __restrict__ dinv, int* __restrict__ srcs,
                const float4* __restrict__ x4, __half* __restrict__ xs,
                int N, int C, int halfN) {
    __shared__ int cnt[BN * 2];
    __shared__ int ps[1024];
    __shared__ int cur[BN * 2];
    __shared__ float sdv[BN];
    int bkt = blockIdx.x;
    int t = threadIdx.x;
    int nodeBase = bkt << BSH;
    cnt[t] = 0;
    __syncthreads();
    int beg = bkt * C;
    int end = min(gCursor[bkt], beg + C);
    for (int e = beg + t; e < end; e += 1024) {
        int w = packed[e];
        int key = ((w & (BN - 1)) << 1) | ((w >> BSH) >= halfN ? 1 : 0);
        atomicAdd(&cnt[key], 1);
    }
    __syncthreads();
    // thread t (< BN) owns bins 2t,2t+1 = node t (local)
    int c0 = (t < BN) ? cnt[2 * t] : 0;
    int c1 = (t < BN) ? cnt[2 * t + 1] : 0;
    int s = c0 + c1;
    ps[t] = s;
    __syncthreads();
    for (int off = 1; off < 1024; off <<= 1) {     // inclusive Hillis-Steele
        int u = (t >= off) ? ps[t - off] : 0;
        __syncthreads();
        ps[t] += u;
        __syncthreads();
    }
    if (t < BN) {
        int p = beg + ps[t] - s;                   // exclusive prefix
        cur[2 * t] = p;
        cur[2 * t + 1] = p + c0;
        float d = rsqrtf((float)s + 1.0f);
        sdv[t] = d;
        int n = nodeBase + t;
        if (n < N) {
            rowRange[n] = make_int2(p, p + s);
            rowMid[n] = p + c0;
            dinv[n] = d;
        }
    }
    __syncthreads();
    for (int e = beg + t; e < end; e += 1024) {    // counting sort (2nd read: L2)
        int w = packed[e];
        int src = w >> BSH;
        int key = ((w & (BN - 1)) << 1) | (src >= halfN ? 1 : 0);
        int pos = atomicAdd(&cur[key], 1);
        srcs[pos] = src;
    }
    // prescale: xs = fp16(dinv .* x); 2 threads/node, 16B (8 halves) each
    {
        int n = t >> 1, hf = t & 1;                 // BN*2 == 1024 exactly
        int g = nodeBase + n;
        if (g < N) {
            float d = sdv[n];
            float4 va = x4[(size_t)g * 4 + hf * 2];
            float4 vb = x4[(size_t)g * 4 + hf * 2 + 1];
            __half2 h0 = __floats2half2_rn(va.x * d, va.y * d);
            __half2 h1 = __floats2half2_rn(va.z * d, va.w * d);
            __half2 h2 = __floats2half2_rn(vb.x * d, vb.y * d);
            __half2 h3 = __floats2half2_rn(vb.z * d, vb.w * d);
            uint4 u;
            u.x = *(unsigned*)&h0; u.y = *(unsigned*)&h1;
            u.z = *(unsigned*)&h2; u.w = *(unsigned*)&h3;
            *(uint4*)(xs + (size_t)g * 16 + hf * 8) = u;
        }
    }
}

__device__ __forceinline__ void acc8(float* a, uint4 u) {
    float2 f;
    f = __half22float2(*(const __half2*)&u.x); a[0] += f.x; a[1] += f.y;
    f = __half22float2(*(const __half2*)&u.y); a[2] += f.x; a[3] += f.y;
    f = __half22float2(*(const __half2*)&u.z); a[4] += f.x; a[5] += f.y;
    f = __half22float2(*(const __half2*)&u.w); a[6] += f.x; a[7] += f.y;
}

// Layer 1: gather xs (16ch half), fused W1 GEMM + bias + ReLU; hs1=fp16(dinv.*h1).
// 2 lanes per node, 16B each; block = 128 nodes.  (round-8 body)
__global__ void __launch_bounds__(256)
gather_conv1(const int2* __restrict__ rowRange, const int* __restrict__ srcs,
             const __half* __restrict__ xs, const float* __restrict__ dinv,
             const float* __restrict__ W1, const float* __restrict__ b1,
             __half* __restrict__ hs1, int N) {
    __shared__ float A[128][17];
    __shared__ float sW[16 * 32];
    __shared__ float sb[32];
    int t = threadIdx.x;
    for (int i = t; i < 512; i += 256) sW[i] = W1[i];
    if (t < 32) sb[t] = b1[t];
    int tt = blockIdx.x * 256 + t;
    int node = tt >> 1, q = tt & 1, ln = t >> 1;
    float a[8] = {0.f, 0.f, 0.f, 0.f, 0.f, 0.f, 0.f, 0.f};
    float di = 0.f;
    if (node < N) {
        int2 rr = rowRange[node];
        for (int e = rr.x; e < rr.y; ++e) {
            int s = srcs[e];
            acc8(a, *(const uint4*)(xs + (size_t)s * 16 + q * 8));
        }
        acc8(a, *(const uint4*)(xs + (size_t)node * 16 + q * 8));   // self
        di = dinv[node];
#pragma unroll
        for (int j = 0; j < 8; ++j) a[j] *= di;
    }
#pragma unroll
    for (int j = 0; j < 8; ++j) A[ln][q * 8 + j] = a[j];
    __syncthreads();
    if (node < N) {
        int k0 = q * 16;
        float acc[16];
#pragma unroll
        for (int j = 0; j < 16; ++j) acc[j] = sb[k0 + j];
#pragma unroll
        for (int c = 0; c < 16; ++c) {
            float ac = A[ln][c];
#pragma unroll
            for (int j = 0; j < 16; ++j) acc[j] += ac * sW[c * 32 + k0 + j];
        }
        __half2 h[8];
#pragma unroll
        for (int j = 0; j < 8; ++j)
            h[j] = __floats2half2_rn(di * fmaxf(acc[2 * j], 0.f),
                                     di * fmaxf(acc[2 * j + 1], 0.f));
        uint4 u0, u1;
        u0.x = *(unsigned*)&h[0]; u0.y = *(unsigned*)&h[1];
        u0.z = *(unsigned*)&h[2]; u0.w = *(unsigned*)&h[3];
        u1.x = *(unsigned*)&h[4]; u1.y = *(unsigned*)&h[5];
        u1.z = *(unsigned*)&h[6]; u1.w = *(unsigned*)&h[7];
        *(uint4*)(hs1 + (size_t)node * 32 + k0) = u0;
        *(uint4*)(hs1 + (size_t)node * 32 + k0 + 8) = u1;
    }
}

// Conv2 phase A: sum lo-half srcs (hs1 rows [0,N/2) = contiguous 3.2 MB,
// per-XCD L2-resident) -> A2[N,32] fp32 coalesced. 4 lanes/node.
__global__ void __launch_bounds__(256)
gather_conv2_lo(const int2* __restrict__ rowRange, const int* __restrict__ rowMid,
                const int* __restrict__ srcs, const __half* __restrict__ hs1,
                float* __restrict__ A2, int N) {
    int tt = blockIdx.x * 256 + threadIdx.x;
    int node = tt >> 2, q = tt & 3;
    if (node >= N) return;
    float a[8] = {0.f, 0.f, 0.f, 0.f, 0.f, 0.f, 0.f, 0.f};
    int beg = rowRange[node].x, mid = rowMid[node];
    for (int e = beg; e < mid; ++e) {
        int s = srcs[e];
        acc8(a, *(const uint4*)(hs1 + (size_t)s * 32 + q * 8));
    }
    float4 r0, r1;
    r0.x = a[0]; r0.y = a[1]; r0.z = a[2]; r0.w = a[3];
    r1.x = a[4]; r1.y = a[5]; r1.z = a[6]; r1.w = a[7];
    *(float4*)(A2 + (size_t)node * 32 + q * 8) = r0;
    *(float4*)(A2 + (size_t)node * 32 + q * 8 + 4) = r1;
}

// Conv2 phase B + head: hi-half srcs (hs1 rows [N/2,N) = 3.2 MB) + self +
// A2 partial; fused W2+b2+ReLU, Wl1+bl1+ReLU, Wl4+bl4. 4 lanes/node.
__global__ void __launch_bounds__(256)
gather_conv2_hi_head(const int2* __restrict__ rowRange, const int* __restrict__ rowMid,
                     const int* __restrict__ srcs, const __half* __restrict__ hs1,
                     const float* __restrict__ A2, const float* __restrict__ dinv,
                     const float* __restrict__ W2, const float* __restrict__ b2,
                     const float* __restrict__ Wl1, const float* __restrict__ bl1,
                     const float* __restrict__ Wl4, const float* __restrict__ bl4,
                     float* __restrict__ out, int N) {
    __shared__ float A[64][33];
    __shared__ float sW2[1024];
    __shared__ float sWl1[1024];
    __shared__ float sb2[32], sbl1[32], sWl4[32];
    __shared__ float sbl4;
    int t = threadIdx.x;
    for (int i = t; i < 1024; i += 256) { sW2[i] = W2[i]; sWl1[i] = Wl1[i]; }
    if (t < 32) { sb2[t] = b2[t]; sbl1[t] = bl1[t]; sWl4[t] = Wl4[t]; }
    if (t == 0) sbl4 = bl4[0];
    int tt = blockIdx.x * 256 + t;
    int node = tt >> 2, q = tt & 3, ln = t >> 2;
    float a[8] = {0.f, 0.f, 0.f, 0.f, 0.f, 0.f, 0.f, 0.f};
    if (node < N) {
        int mid = rowMid[node], end = rowRange[node].y;
        for (int e = mid; e < end; ++e) {
            int s = srcs[e];
            acc8(a, *(const uint4*)(hs1 + (size_t)s * 32 + q * 8));
        }
        acc8(a, *(const uint4*)(hs1 + (size_t)node * 32 + q * 8));  // self
        // partial from phase A (coalesced)
        float4 l0 = *(const float4*)(A2 + (size_t)node * 32 + q * 8);
        float4 l1 = *(const float4*)(A2 + (size_t)node * 32 + q * 8 + 4);
        a[0] += l0.x; a[1] += l0.y; a[2] += l0.z; a[3] += l0.w;
        a[4] += l1.x; a[5] += l1.y; a[6] += l1.z; a[7] += l1.w;
        float di = dinv[node];
#pragma unroll
        for (int j = 0; j < 8; ++j) a[j] *= di;
    }
#pragma unroll
    for (int j = 0; j < 8; ++j) A[ln][q * 8 + j] = a[j];
    __syncthreads();
    int k0 = q * 8;
    float h2[8];
#pragma unroll
    for (int j = 0; j < 8; ++j) h2[j] = sb2[k0 + j];
#pragma unroll
    for (int c = 0; c < 32; ++c) {
        float ac = A[ln][c];
#pragma unroll
        for (int j = 0; j < 8; ++j) h2[j] += ac * sW2[c * 32 + k0 + j];
    }
#pragma unroll
    for (int j = 0; j < 8; ++j) h2[j] = fmaxf(h2[j], 0.f);
    __syncthreads();
#pragma unroll
    for (int j = 0; j < 8; ++j) A[ln][k0 + j] = h2[j];
    __syncthreads();
    float h3[8];
#pragma unroll
    for (int j = 0; j < 8; ++j) h3[j] = sbl1[k0 + j];
#pragma unroll
    for (int c = 0; c < 32; ++c) {
        float ac = A[ln][c];
#pragma unroll
        for (int j = 0; j < 8; ++j) h3[j] += ac * sWl1[c * 32 + k0 + j];
    }
    float p = 0.f;
#pragma unroll
    for (int j = 0; j < 8; ++j) p += fmaxf(h3[j], 0.f) * sWl4[k0 + j];
    p += __shfl_xor(p, 1);
    p += __shfl_xor(p, 2);
    if (q == 0 && node < N) out[node] = p + sbl4;
}

extern "C" void kernel_launch(void* const* d_in, const int* in_sizes, int n_in,
                              void* d_out, int out_size, void* d_ws, size_t ws_size,
                              hipStream_t stream) {
    const float* x   = (const float*)d_in[0];
    const int*   ei  = (const int*)d_in[1];
    const float* W1  = (const float*)d_in[2];
    const float* b1  = (const float*)d_in[3];
    const float* W2  = (const float*)d_in[4];
    const float* b2  = (const float*)d_in[5];
    const float* Wl1 = (const float*)d_in[6];
    const float* bl1 = (const float*)d_in[7];
    const float* Wl4 = (const float*)d_in[8];
    const float* bl4 = (const float*)d_in[9];
    float* out = (float*)d_out;

    const int N = in_sizes[0] / 16;
    const int E = in_sizes[1] / 2;
    const int* row = ei;        // edge_index[0] : source j
    const int* col = ei + E;    // edge_index[1] : target i
    const int NB = (N + BN - 1) >> BSH;
    const int halfN = N / 2;
    // fixed per-bucket capacity: mean * 1.125, rounded up to 64
    int C = (E + NB - 1) / NB;
    C = (C * 9 + 7) / 8;
    C = (C + 63) & ~63;

    // workspace layout (512B aligned)
    char* ws = (char*)d_ws;
    auto align = [](size_t v) { return (v + 511) & ~(size_t)511; };
    size_t o = 0;
    int*    gCursor  = (int*)(ws + o);    o = align(o + (size_t)NBUF * 4);
    int2*   rowRange = (int2*)(ws + o);   o = align(o + (size_t)N * 8);
    int*    rowMid   = (int*)(ws + o);    o = align(o + (size_t)N * 4);
    float*  dinv     = (float*)(ws + o);  o = align(o + (size_t)N * 4);
    int*    packed   = (int*)(ws + o);    o = align(o + (size_t)NB * C * 4);
    int*    srcs     = (int*)(ws + o);    o = align(o + (size_t)NB * C * 4);
    __half* xs       = (__half*)(ws + o); o = align(o + (size_t)N * 16 * 2);
    __half* hs1      = (__half*)(ws + o); o = align(o + (size_t)N * 32 * 2);
    float*  A2       = (float*)(ws + o);  o = align(o + (size_t)N * 32 * 4);

    const int BLK = 256;
    int gridSc = (E + EPB - 1) / EPB;
    int gridG1 = (N * 2 + BLK - 1) / BLK;
    int gridG2 = (N * 4 + BLK - 1) / BLK;

    // --- edge reorder + degrees + prescale ---
    init_cursor<<<1, BLK, 0, stream>>>(gCursor, NB, C);
    bucket_scatter<<<gridSc, BLK, 0, stream>>>(row, col, gCursor, packed, E, NB, C);
    bucket_finalize<<<NB, 1024, 0, stream>>>(packed, gCursor, rowRange, rowMid, dinv,
                                             srcs, (const float4*)x, xs, N, C, halfN);

    // --- conv1 (gather xs + fused W1) ---
    gather_conv1<<<gridG1, BLK, 0, stream>>>(rowRange, srcs, xs, dinv, W1, b1, hs1, N);

    // --- conv2 two-phase (each phase's random set = one 3.2 MB half of hs1) ---
    gather_conv2_lo<<<gridG2, BLK, 0, stream>>>(rowRange, rowMid, srcs, hs1, A2, N);
    gather_conv2_hi_head<<<gridG2, BLK, 0, stream>>>(rowRange, rowMid, srcs, hs1, A2,
                                                     dinv, W2, b2, Wl1, bl1,
                                                     Wl4, bl4, out, N);
}

// Round 15
// 246.635 us; speedup vs baseline: 1.5265x; 1.0193x over previous
//
#include <hip/hip_runtime.h>
#include <hip/hip_fp16.h>
#include <math.h>

// ---------------------------------------------------------------------------
// GCN forward, fully fused, fp16 feature tables (fp32 accumulate).
//   xs  = fp16(dinv .* x)   [N,16] half (3.2 MB, L2-resident)
//   hs1 = fp16(dinv .* h1)  [N,32] half (6.4 MB)
// Edge layout: bucket b = 512 dst nodes, fixed-capacity gapped region of C
// edges at b*C. Lists sorted by (dstLocal, srcHalf): rowRange[n]=(beg,end),
// rowMid[n] = boundary between srcs < N/2 and srcs >= N/2.
// conv2 runs as two kernels so each one's random working set is one 3.2 MB
// contiguous half of hs1 (fits a 4 MiB per-XCD L2).
// ---------------------------------------------------------------------------

#define BN 512           // nodes per bucket
#define BSH 9            // log2(BN)
#define NBUF 256         // max buckets (N <= 131072)
#define EPB 4096         // edges per scatter block
#define EPT 8            // edges per scatter thread (EPB/512)

__global__ void init_cursor(int* __restrict__ gCursor, int NB, int C) {
    int b = blockIdx.x * blockDim.x + threadIdx.x;
    if (b < NB) gCursor[b] = b * C;
}

// Scatter edges into bucket-gapped packed array ((src<<9)|dstLocal).
// 512 threads/block for TLP; single LDS-atomic pass, rank in registers.
__global__ void __launch_bounds__(512)
bucket_scatter(const int* __restrict__ row, const int* __restrict__ col,
               int* __restrict__ gCursor, int* __restrict__ packed,
               int E, int NB, int C) {
    __shared__ int hist[NBUF];
    __shared__ int base[NBUF];
    int t = threadIdx.x;
    int blockBase = blockIdx.x * EPB;
    for (int i = t; i < NB; i += 512) hist[i] = 0;
    __syncthreads();
    int pay[EPT];
    int meta[EPT];
#pragma unroll
    for (int k = 0; k < EPT; ++k) {
        int e = blockBase + k * 512 + t;
        if (e < E) {
            int c = col[e];
            int b = c >> BSH;
            int r = atomicAdd(&hist[b], 1);        // rank within (block,bucket)
            pay[k] = (row[e] << BSH) | (c & (BN - 1));
            meta[k] = (b << 16) | r;               // r < 4096 fits 16 bits
        } else {
            meta[k] = -1;
        }
    }
    __syncthreads();
    for (int b = t; b < NB; b += 512) {            // claim global ranges
        int c = hist[b];
        base[b] = c ? atomicAdd(&gCursor[b], c) : 0;
    }
    __syncthreads();
#pragma unroll
    for (int k = 0; k < EPT; ++k) {                // write
        int m = meta[k];
        if (m >= 0) {
            int b = m >> 16;
            int pos = base[b] + (m & 0xFFFF);
            if (pos < (b + 1) * C)                 // overflow guard (~16 sigma)
                packed[pos] = pay[k];
        }
    }
}

// Per bucket (1024 threads): 1024-bin hist (dstLocal*2 + srcHalf) -> rowRange
// + rowMid + dinv, counting-sort -> srcs[] ordered (dl, srcHalf), prescale xs.
__global__ void __launch_bounds__(1024)
bucket_finalize(const int* __restrict__ packed, const int* __restrict__ gCursor,
                int2* __restrict__ rowRange, int* __restrict__ rowMid,
                float* __restrict__ dinv, int* __restrict__ srcs,
                const float4* __restrict__ x4, __half* __restrict__ xs,
                int N, int C, int halfN) {
    __shared__ int cnt[BN * 2];
    __shared__ int ps[1024];
    __shared__ int cur[BN * 2];
    __shared__ float sdv[BN];
    int bkt = blockIdx.x;
    int t = threadIdx.x;
    int nodeBase = bkt << BSH;
    cnt[t] = 0;
    __syncthreads();
    int beg = bkt * C;
    int end = min(gCursor[bkt], beg + C);
    for (int e = beg + t; e < end; e += 1024) {
        int w = packed[e];
        int key = ((w & (BN - 1)) << 1) | ((w >> BSH) >= halfN ? 1 : 0);
        atomicAdd(&cnt[key], 1);
    }
    __syncthreads();
    // thread t (< BN) owns bins 2t,2t+1 = node t (local)
    int c0 = (t < BN) ? cnt[2 * t] : 0;
    int c1 = (t < BN) ? cnt[2 * t + 1] : 0;
    int s = c0 + c1;
    ps[t] = s;
    __syncthreads();
    for (int off = 1; off < 1024; off <<= 1) {     // inclusive Hillis-Steele
        int u = (t >= off) ? ps[t - off] : 0;
        __syncthreads();
        ps[t] += u;
        __syncthreads();
    }
    if (t < BN) {
        int p = beg + ps[t] - s;                   // exclusive prefix
        cur[2 * t] = p;
        cur[2 * t + 1] = p + c0;
        float d = rsqrtf((float)s + 1.0f);
        sdv[t] = d;
        int n = nodeBase + t;
        if (n < N) {
            rowRange[n] = make_int2(p, p + s);
            rowMid[n] = p + c0;
            dinv[n] = d;
        }
    }
    __syncthreads();
    for (int e = beg + t; e < end; e += 1024) {    // counting sort (2nd read: L2)
        int w = packed[e];
        int src = w >> BSH;
        int key = ((w & (BN - 1)) << 1) | (src >= halfN ? 1 : 0);
        int pos = atomicAdd(&cur[key], 1);
        srcs[pos] = src;
    }
    // prescale: xs = fp16(dinv .* x); 2 threads/node, 16B (8 halves) each
    {
        int n = t >> 1, hf = t & 1;                 // BN*2 == 1024 exactly
        int g = nodeBase + n;
        if (g < N) {
            float d = sdv[n];
            float4 va = x4[(size_t)g * 4 + hf * 2];
            float4 vb = x4[(size_t)g * 4 + hf * 2 + 1];
            __half2 h0 = __floats2half2_rn(va.x * d, va.y * d);
            __half2 h1 = __floats2half2_rn(va.z * d, va.w * d);
            __half2 h2 = __floats2half2_rn(vb.x * d, vb.y * d);
            __half2 h3 = __floats2half2_rn(vb.z * d, vb.w * d);
            uint4 u;
            u.x = *(unsigned*)&h0; u.y = *(unsigned*)&h1;
            u.z = *(unsigned*)&h2; u.w = *(unsigned*)&h3;
            *(uint4*)(xs + (size_t)g * 16 + hf * 8) = u;
        }
    }
}

__device__ __forceinline__ void acc8(float* a, uint4 u) {
    float2 f;
    f = __half22float2(*(const __half2*)&u.x); a[0] += f.x; a[1] += f.y;
    f = __half22float2(*(const __half2*)&u.y); a[2] += f.x; a[3] += f.y;
    f = __half22float2(*(const __half2*)&u.z); a[4] += f.x; a[5] += f.y;
    f = __half22float2(*(const __half2*)&u.w); a[6] += f.x; a[7] += f.y;
}

__device__ __forceinline__ void acc4(float* a, uint2 u) {
    float2 f;
    f = __half22float2(*(const __half2*)&u.x); a[0] += f.x; a[1] += f.y;
    f = __half22float2(*(const __half2*)&u.y); a[2] += f.x; a[3] += f.y;
}

// Layer 1: gather xs (16ch half), fused W1 GEMM + bias + ReLU; hs1=fp16(dinv.*h1).
// 4 lanes per node, 8B (4 halves) each; block = 64 nodes, grid 1563.
__global__ void __launch_bounds__(256)
gather_conv1(const int2* __restrict__ rowRange, const int* __restrict__ srcs,
             const __half* __restrict__ xs, const float* __restrict__ dinv,
             const float* __restrict__ W1, const float* __restrict__ b1,
             __half* __restrict__ hs1, int N) {
    __shared__ float A[64][17];
    __shared__ float sW[512];
    __shared__ float sb[32];
    int t = threadIdx.x;
    for (int i = t; i < 512; i += 256) sW[i] = W1[i];
    if (t < 32) sb[t] = b1[t];
    int tt = blockIdx.x * 256 + t;
    int node = tt >> 2, q = tt & 3, ln = t >> 2;
    float a[4] = {0.f, 0.f, 0.f, 0.f};
    float di = 0.f;
    if (node < N) {
        int2 rr = rowRange[node];
        for (int e = rr.x; e < rr.y; ++e) {
            int s = srcs[e];
            acc4(a, *(const uint2*)(xs + (size_t)s * 16 + q * 4));
        }
        acc4(a, *(const uint2*)(xs + (size_t)node * 16 + q * 4));   // self
        di = dinv[node];
#pragma unroll
        for (int j = 0; j < 4; ++j) a[j] *= di;
    }
#pragma unroll
    for (int j = 0; j < 4; ++j) A[ln][q * 4 + j] = a[j];
    __syncthreads();
    if (node < N) {
        int k0 = q * 8;
        float acc[8];
#pragma unroll
        for (int j = 0; j < 8; ++j) acc[j] = sb[k0 + j];
#pragma unroll
        for (int c = 0; c < 16; ++c) {
            float ac = A[ln][c];
#pragma unroll
            for (int j = 0; j < 8; ++j) acc[j] += ac * sW[c * 32 + k0 + j];
        }
        __half2 h[4];
#pragma unroll
        for (int j = 0; j < 4; ++j)
            h[j] = __floats2half2_rn(di * fmaxf(acc[2 * j], 0.f),
                                     di * fmaxf(acc[2 * j + 1], 0.f));
        uint4 u;
        u.x = *(unsigned*)&h[0]; u.y = *(unsigned*)&h[1];
        u.z = *(unsigned*)&h[2]; u.w = *(unsigned*)&h[3];
        *(uint4*)(hs1 + (size_t)node * 32 + k0) = u;
    }
}

// Conv2 phase A: sum lo-half srcs (hs1 rows [0,N/2) = contiguous 3.2 MB,
// per-XCD L2-resident) -> A2[N,32] fp32 coalesced. 4 lanes/node.
__global__ void __launch_bounds__(256)
gather_conv2_lo(const int2* __restrict__ rowRange, const int* __restrict__ rowMid,
                const int* __restrict__ srcs, const __half* __restrict__ hs1,
                float* __restrict__ A2, int N) {
    int tt = blockIdx.x * 256 + threadIdx.x;
    int node = tt >> 2, q = tt & 3;
    if (node >= N) return;
    float a[8] = {0.f, 0.f, 0.f, 0.f, 0.f, 0.f, 0.f, 0.f};
    int beg = rowRange[node].x, mid = rowMid[node];
    for (int e = beg; e < mid; ++e) {
        int s = srcs[e];
        acc8(a, *(const uint4*)(hs1 + (size_t)s * 32 + q * 8));
    }
    float4 r0, r1;
    r0.x = a[0]; r0.y = a[1]; r0.z = a[2]; r0.w = a[3];
    r1.x = a[4]; r1.y = a[5]; r1.z = a[6]; r1.w = a[7];
    *(float4*)(A2 + (size_t)node * 32 + q * 8) = r0;
    *(float4*)(A2 + (size_t)node * 32 + q * 8 + 4) = r1;
}

// Conv2 phase B + head: hi-half srcs (hs1 rows [N/2,N) = 3.2 MB) + self +
// A2 partial; fused W2+b2+ReLU, Wl1+bl1+ReLU, Wl4+bl4. 4 lanes/node.
__global__ void __launch_bounds__(256)
gather_conv2_hi_head(const int2* __restrict__ rowRange, const int* __restrict__ rowMid,
                     const int* __restrict__ srcs, const __half* __restrict__ hs1,
                     const float* __restrict__ A2, const float* __restrict__ dinv,
                     const float* __restrict__ W2, const float* __restrict__ b2,
                     const float* __restrict__ Wl1, const float* __restrict__ bl1,
                     const float* __restrict__ Wl4, const float* __restrict__ bl4,
                     float* __restrict__ out, int N) {
    __shared__ float A[64][33];
    __shared__ float sW2[1024];
    __shared__ float sWl1[1024];
    __shared__ float sb2[32], sbl1[32], sWl4[32];
    __shared__ float sbl4;
    int t = threadIdx.x;
    for (int i = t; i < 1024; i += 256) { sW2[i] = W2[i]; sWl1[i] = Wl1[i]; }
    if (t < 32) { sb2[t] = b2[t]; sbl1[t] = bl1[t]; sWl4[t] = Wl4[t]; }
    if (t == 0) sbl4 = bl4[0];
    int tt = blockIdx.x * 256 + t;
    int node = tt >> 2, q = tt & 3, ln = t >> 2;
    float a[8] = {0.f, 0.f, 0.f, 0.f, 0.f, 0.f, 0.f, 0.f};
    if (node < N) {
        int mid = rowMid[node], end = rowRange[node].y;
        for (int e = mid; e < end; ++e) {
            int s = srcs[e];
            acc8(a, *(const uint4*)(hs1 + (size_t)s * 32 + q * 8));
        }
        acc8(a, *(const uint4*)(hs1 + (size_t)node * 32 + q * 8));  // self
        // partial from phase A (coalesced)
        float4 l0 = *(const float4*)(A2 + (size_t)node * 32 + q * 8);
        float4 l1 = *(const float4*)(A2 + (size_t)node * 32 + q * 8 + 4);
        a[0] += l0.x; a[1] += l0.y; a[2] += l0.z; a[3] += l0.w;
        a[4] += l1.x; a[5] += l1.y; a[6] += l1.z; a[7] += l1.w;
        float di = dinv[node];
#pragma unroll
        for (int j = 0; j < 8; ++j) a[j] *= di;
    }
#pragma unroll
    for (int j = 0; j < 8; ++j) A[ln][q * 8 + j] = a[j];
    __syncthreads();
    int k0 = q * 8;
    float h2[8];
#pragma unroll
    for (int j = 0; j < 8; ++j) h2[j] = sb2[k0 + j];
#pragma unroll
    for (int c = 0; c < 32; ++c) {
        float ac = A[ln][c];
#pragma unroll
        for (int j = 0; j < 8; ++j) h2[j] += ac * sW2[c * 32 + k0 + j];
    }
#pragma unroll
    for (int j = 0; j < 8; ++j) h2[j] = fmaxf(h2[j], 0.f);
    __syncthreads();
#pragma unroll
    for (int j = 0; j < 8; ++j) A[ln][k0 + j] = h2[j];
    __syncthreads();
    float h3[8];
#pragma unroll
    for (int j = 0; j < 8; ++j) h3[j] = sbl1[k0 + j];
#pragma unroll
    for (int c = 0; c < 32; ++c) {
        float ac = A[ln][c];
#pragma unroll
        for (int j = 0; j < 8; ++j) h3[j] += ac * sWl1[c * 32 + k0 + j];
    }
    float p = 0.f;
#pragma unroll
    for (int j = 0; j < 8; ++j) p += fmaxf(h3[j], 0.f) * sWl4[k0 + j];
    p += __shfl_xor(p, 1);
    p += __shfl_xor(p, 2);
    if (q == 0 && node < N) out[node] = p + sbl4;
}

extern "C" void kernel_launch(void* const* d_in, const int* in_sizes, int n_in,
                              void* d_out, int out_size, void* d_ws, size_t ws_size,
                              hipStream_t stream) {
    const float* x   = (const float*)d_in[0];
    const int*   ei  = (const int*)d_in[1];
    const float* W1  = (const float*)d_in[2];
    const float* b1  = (const float*)d_in[3];
    const float* W2  = (const float*)d_in[4];
    const float* b2  = (const float*)d_in[5];
    const float* Wl1 = (const float*)d_in[6];
    const float* bl1 = (const float*)d_in[7];
    const float* Wl4 = (const float*)d_in[8];
    const float* bl4 = (const float*)d_in[9];
    float* out = (float*)d_out;

    const int N = in_sizes[0] / 16;
    const int E = in_sizes[1] / 2;
    const int* row = ei;        // edge_index[0] : source j
    const int* col = ei + E;    // edge_index[1] : target i
    const int NB = (N + BN - 1) >> BSH;
    const int halfN = N / 2;
    // fixed per-bucket capacity: mean * 1.125, rounded up to 64
    int C = (E + NB - 1) / NB;
    C = (C * 9 + 7) / 8;
    C = (C + 63) & ~63;

    // workspace layout (512B aligned)
    char* ws = (char*)d_ws;
    auto align = [](size_t v) { return (v + 511) & ~(size_t)511; };
    size_t o = 0;
    int*    gCursor  = (int*)(ws + o);    o = align(o + (size_t)NBUF * 4);
    int2*   rowRange = (int2*)(ws + o);   o = align(o + (size_t)N * 8);
    int*    rowMid   = (int*)(ws + o);    o = align(o + (size_t)N * 4);
    float*  dinv     = (float*)(ws + o);  o = align(o + (size_t)N * 4);
    int*    packed   = (int*)(ws + o);    o = align(o + (size_t)NB * C * 4);
    int*    srcs     = (int*)(ws + o);    o = align(o + (size_t)NB * C * 4);
    __half* xs       = (__half*)(ws + o); o = align(o + (size_t)N * 16 * 2);
    __half* hs1      = (__half*)(ws + o); o = align(o + (size_t)N * 32 * 2);
    float*  A2       = (float*)(ws + o);  o = align(o + (size_t)N * 32 * 4);

    const int BLK = 256;
    int gridSc = (E + EPB - 1) / EPB;
    int gridG  = (N * 4 + BLK - 1) / BLK;

    // --- edge reorder + degrees + prescale ---
    init_cursor<<<1, BLK, 0, stream>>>(gCursor, NB, C);
    bucket_scatter<<<gridSc, 512, 0, stream>>>(row, col, gCursor, packed, E, NB, C);
    bucket_finalize<<<NB, 1024, 0, stream>>>(packed, gCursor, rowRange, rowMid, dinv,
                                             srcs, (const float4*)x, xs, N, C, halfN);

    // --- conv1 (gather xs + fused W1) ---
    gather_conv1<<<gridG, BLK, 0, stream>>>(rowRange, srcs, xs, dinv, W1, b1, hs1, N);

    // --- conv2 two-phase (each phase's random set = one 3.2 MB half of hs1) ---
    gather_conv2_lo<<<gridG, BLK, 0, stream>>>(rowRange, rowMid, srcs, hs1, A2, N);
    gather_conv2_hi_head<<<gridG, BLK, 0, stream>>>(rowRange, rowMid, srcs, hs1, A2,
                                                    dinv, W2, b2, Wl1, bl1,
                                                    Wl4, bl4, out, N);
}